// Round 7
// baseline (635.913 us; speedup 1.0000x reference)
//
#include <hip/hip_runtime.h>
#include <hip/hip_fp16.h>
#include <math.h>

#define BSH    9          // bucket = 512 nodes
#define BNODES 512
#define NBMAX  128
#define CAP2   24576      // per-bucket stage capacity
#define ECHUNK 6144       // edges per k_bin block

typedef short bf16x8 __attribute__((ext_vector_type(8)));
typedef float f32x4 __attribute__((ext_vector_type(4)));

__device__ __forceinline__ unsigned f2b(float f) {   // float -> bf16 bits, RTN-even
    union { float f; unsigned u; } x; x.f = f;
    return (x.u + 0x7fffu + ((x.u >> 16) & 1u)) >> 16;
}

// ---------------- zero ----------------

__global__ __launch_bounds__(256) void k_zero(int* __restrict__ p, int n) {
    int i = blockIdx.x * 256 + threadIdx.x;
    if (i < n) p[i] = 0;
}

// ---------------- casts ----------------

__global__ __launch_bounds__(256) void k_castx(const float4* __restrict__ x, uint4* __restrict__ xb, int n8) {
    int i = blockIdx.x * 256 + threadIdx.x;
    if (i >= n8) return;
    float4 f0 = x[2 * i], f1 = x[2 * i + 1];
    uint4 o;
    o.x = f2b(f0.x) | (f2b(f0.y) << 16);
    o.y = f2b(f0.z) | (f2b(f0.w) << 16);
    o.z = f2b(f1.x) | (f2b(f1.y) << 16);
    o.w = f2b(f1.z) | (f2b(f1.w) << 16);
    xb[i] = o;
}

// fused: w1t[n*256+k]=bf16(W1[k*256+n]); w2t[n*256+k]=bf16(W2[k*48+n])
__global__ __launch_bounds__(256) void k_castw(const float* __restrict__ W1, const float* __restrict__ W2,
                                               unsigned short* __restrict__ w1t, unsigned short* __restrict__ w2t) {
    int i = blockIdx.x * 256 + threadIdx.x;
    if (i < 65536) {
        int n = i >> 8, k = i & 255;
        w1t[i] = (unsigned short)f2b(W1[k * 256 + n]);
    } else if (i < 65536 + 12288) {
        int j = i - 65536;
        int n = j >> 8, k = j & 255;
        w2t[j] = (unsigned short)f2b(W2[k * 48 + n]);
    }
}

// ---------------- pass 1: block-local binning by dst>>9 ----------------

__global__ __launch_bounds__(256) void k_bin(const int* __restrict__ src, const int* __restrict__ dst,
                                             int* __restrict__ bktcnt, unsigned* __restrict__ stage,
                                             int E, int NB) {
    __shared__ unsigned ecache[ECHUNK];
    __shared__ int lcnt[NBMAX], lbase[NBMAX], lcur[NBMAX];
    const int t = threadIdx.x;
    for (int i = t; i < NBMAX; i += 256) { lcnt[i] = 0; lcur[i] = 0; }
    const int e0 = blockIdx.x * ECHUNK;
    const int m = min(ECHUNK, E - e0);
    __syncthreads();
    for (int i = t; i < m; i += 256) {
        int s = src[e0 + i], d = dst[e0 + i];
        ecache[i] = ((unsigned)d << 16) | (unsigned)s;
        atomicAdd(&lcnt[d >> BSH], 1);
    }
    __syncthreads();
    if (t < NB) lbase[t] = lcnt[t] ? atomicAdd(&bktcnt[t], lcnt[t]) : 0;
    __syncthreads();
    for (int i = t; i < m; i += 256) {
        unsigned p = ecache[i];
        int b = (int)(p >> (16 + BSH));
        int pos = lbase[b] + atomicAdd(&lcur[b], 1);
        if (pos < CAP2) stage[(size_t)b * CAP2 + pos] = p;
    }
}

// ---------------- pass 2a: degrees per bucket + fused dinv/dinv2/sdeg ----------------

__global__ __launch_bounds__(512) void k_cnt(const unsigned* __restrict__ stage,
                                             const int* __restrict__ bktcnt,
                                             int* __restrict__ cnt,
                                             float* __restrict__ dinv, float* __restrict__ dinv2,
                                             float* __restrict__ sdeg, int N) {
    __shared__ int dcnt[BNODES];
    const int b = blockIdx.x, t = threadIdx.x;
    dcnt[t] = 0;
    __syncthreads();
    const int m = min(bktcnt[b], CAP2);
    const unsigned* st = stage + (size_t)b * CAP2;
    for (int i = t; i < m; i += 512)
        atomicAdd(&dcnt[(st[i] >> 16) & (BNODES - 1)], 1);
    __syncthreads();
    int node = b * BNODES + t;
    if (node <= N) {                       // include sentinel N (deg 0 -> row stays zero)
        int c = dcnt[t];
        cnt[node] = c;
        float d = (float)c + 1.0f;
        float r = rsqrtf(d);
        dinv[node] = r;
        dinv2[node] = r * r;
        sdeg[node] = d * r;
    }
}

// ---------------- scan over exact row counts (no padding: tail groups exec-masked) ----------------

__global__ __launch_bounds__(256) void k_scan1(const int* __restrict__ cnt, int* __restrict__ rowptr,
                                               int* __restrict__ blk, int NT) {
    __shared__ int s[256];
    int t = threadIdx.x, i = blockIdx.x * 256 + t;
    int v = (i < NT) ? cnt[i] : 0;   // exact counts; pad slots would cost TA requests (r6 lesson)
    s[t] = v; __syncthreads();
#pragma unroll
    for (int off = 1; off < 256; off <<= 1) {
        int x = (t >= off) ? s[t - off] : 0; __syncthreads();
        s[t] += x; __syncthreads();
    }
    if (i < NT) rowptr[i] = s[t] - v;
    if (t == 255) blk[blockIdx.x] = s[255];
}

__global__ __launch_bounds__(256) void k_scan2(int* __restrict__ blk, int nb) {
    __shared__ int s[256];
    int t = threadIdx.x;
    int v = (t < nb) ? blk[t] : 0;
    s[t] = v; __syncthreads();
#pragma unroll
    for (int off = 1; off < 256; off <<= 1) {
        int x = (t >= off) ? s[t - off] : 0; __syncthreads();
        s[t] += x; __syncthreads();
    }
    if (t < nb) blk[t] = s[t] - v;
}

__global__ __launch_bounds__(256) void k_scan3(int* __restrict__ rowptr, const int* __restrict__ blk, int NT) {
    int i = blockIdx.x * 256 + threadIdx.x;
    if (i < NT) rowptr[i] += blk[blockIdx.x];
}

// ---------------- pass 2b: place into CSR (ushort), exact rows ----------------

__global__ __launch_bounds__(512) void k_place(const unsigned* __restrict__ stage,
                                               const int* __restrict__ bktcnt,
                                               const int* __restrict__ rowptr,
                                               unsigned short* __restrict__ csr, int N) {
    __shared__ int lcur[BNODES];
    const int b = blockIdx.x, t = threadIdx.x;
    const int node = b * BNODES + t;
    lcur[t] = (node < N) ? rowptr[node] : 0;
    __syncthreads();
    const int m = min(bktcnt[b], CAP2);
    const unsigned* st = stage + (size_t)b * CAP2;
    for (int i = t; i < m; i += 512) {
        unsigned p = st[i];
        int dl = (int)((p >> 16) & (BNODES - 1));
        int pos = atomicAdd(&lcur[dl], 1);
        csr[pos] = (unsigned short)(p & 0xffffu);
    }
}

// ---------------- MFMA GEMM1: h1b = bf16(relu(xb @ W1 + b1)) ----------------
// 128x128 tile, BK=32; LDS-coalesced epilogue. (bf16 A input: fused-f32-cast variant measured slower, r2)

__global__ __launch_bounds__(256) void k_mgemm1(const unsigned short* __restrict__ xb,
                                                const unsigned short* __restrict__ w1t,
                                                const float* __restrict__ bias,
                                                unsigned short* __restrict__ h1b, int M) {
    __shared__ unsigned short sbuf[128 * 136];   // K-loop: As=first 5120, Bs=next 5120; epilogue: 128x136 tile
    unsigned short* As = sbuf;
    unsigned short* Bs = sbuf + 128 * 40;
    const int t = threadIdx.x;
    const int bm = blockIdx.x * 128;
    const int bn = blockIdx.y * 128;
    const int w = t >> 6, lane = t & 63;
    const int q = lane >> 4, l16 = lane & 15;

    f32x4 acc[2][8] = {};
    const int ar0 = t >> 2;
    const int kc  = t & 3;
    const int swz_st = ((kc ^ (ar0 & 3)) * 8);
    int gr0 = bm + ar0;       if (gr0 >= M) gr0 = M - 1;
    int gr1 = bm + ar0 + 64;  if (gr1 >= M) gr1 = M - 1;
    const int swz_rd = (q ^ (l16 & 3)) * 8;

    for (int k0 = 0; k0 < 256; k0 += 32) {
        uint4 a0 = *(const uint4*)&xb[(size_t)gr0 * 256 + k0 + kc * 8];
        uint4 a1 = *(const uint4*)&xb[(size_t)gr1 * 256 + k0 + kc * 8];
        uint4 b0 = *(const uint4*)&w1t[(size_t)(bn + ar0) * 256 + k0 + kc * 8];
        uint4 b1 = *(const uint4*)&w1t[(size_t)(bn + ar0 + 64) * 256 + k0 + kc * 8];
        __syncthreads();
        *(uint4*)&As[ar0 * 40 + swz_st] = a0;
        *(uint4*)&As[(ar0 + 64) * 40 + swz_st] = a1;
        *(uint4*)&Bs[ar0 * 40 + swz_st] = b0;
        *(uint4*)&Bs[(ar0 + 64) * 40 + swz_st] = b1;
        __syncthreads();
        bf16x8 af0 = *(bf16x8*)&As[(w * 32 + l16) * 40 + swz_rd];
        bf16x8 af1 = *(bf16x8*)&As[(w * 32 + 16 + l16) * 40 + swz_rd];
#pragma unroll
        for (int j = 0; j < 8; ++j) {
            bf16x8 bf = *(bf16x8*)&Bs[(j * 16 + l16) * 40 + swz_rd];
            acc[0][j] = __builtin_amdgcn_mfma_f32_16x16x32_bf16(af0, bf, acc[0][j], 0, 0, 0);
            acc[1][j] = __builtin_amdgcn_mfma_f32_16x16x32_bf16(af1, bf, acc[1][j], 0, 0, 0);
        }
    }
    // epilogue: fragments -> LDS tile -> coalesced 128B/thread stores
    __syncthreads();
#pragma unroll
    for (int j = 0; j < 8; ++j) {
        int col = j * 16 + l16;
        float bb = bias[bn + col];
#pragma unroll
        for (int i = 0; i < 2; ++i) {
#pragma unroll
            for (int r = 0; r < 4; ++r) {
                float v = fmaxf(acc[i][j][r] + bb, 0.f);
                sbuf[(w * 32 + i * 16 + q * 4 + r) * 136 + col] = (unsigned short)f2b(v);
            }
        }
    }
    __syncthreads();
    const int row = t >> 1;
    const int ch = (t & 1) * 64;
    if (bm + row < M) {
#pragma unroll
        for (int i = 0; i < 8; ++i) {
            uint4 v = *(uint4*)&sbuf[row * 136 + ch + i * 8];
            *(uint4*)&h1b[(size_t)(bm + row) * 256 + bn + ch + i * 8] = v;
        }
    }
}

// ---------------- MFMA GEMM2: u0 = fp16(dinv .* (h1b @ W2 + b2)), row stride 48 halves ----------------

__global__ __launch_bounds__(256) void k_mgemm2(const unsigned short* __restrict__ h1b,
                                                const unsigned short* __restrict__ w2t,
                                                const float* __restrict__ bias,
                                                const float* __restrict__ dinv,
                                                __half* __restrict__ u0, int M) {
    __shared__ unsigned short As[128 * 40];
    __shared__ unsigned short Bs[48 * 40];
    const int t = threadIdx.x;
    const int bm = blockIdx.x * 128;
    const int w = t >> 6, lane = t & 63;
    const int q = lane >> 4, l16 = lane & 15;

    f32x4 acc[2][3] = {};
    const int ar0 = t >> 2;
    const int kc  = t & 3;
    const int swz_st = ((kc ^ (ar0 & 3)) * 8);
    int gr0 = bm + ar0;      if (gr0 >= M) gr0 = M - 1;
    int gr1 = bm + ar0 + 64; if (gr1 >= M) gr1 = M - 1;
    const int swz_rd = (q ^ (l16 & 3)) * 8;

    for (int k0 = 0; k0 < 256; k0 += 32) {
        uint4 a0 = *(const uint4*)&h1b[(size_t)gr0 * 256 + k0 + kc * 8];
        uint4 a1 = *(const uint4*)&h1b[(size_t)gr1 * 256 + k0 + kc * 8];
        uint4 bv;
        if (t < 192) bv = *(const uint4*)&w2t[(size_t)ar0 * 256 + k0 + kc * 8];
        __syncthreads();
        *(uint4*)&As[ar0 * 40 + swz_st] = a0;
        *(uint4*)&As[(ar0 + 64) * 40 + swz_st] = a1;
        if (t < 192) *(uint4*)&Bs[ar0 * 40 + swz_st] = bv;
        __syncthreads();
        bf16x8 af0 = *(bf16x8*)&As[(w * 32 + l16) * 40 + swz_rd];
        bf16x8 af1 = *(bf16x8*)&As[(w * 32 + 16 + l16) * 40 + swz_rd];
#pragma unroll
        for (int j = 0; j < 3; ++j) {
            bf16x8 bf = *(bf16x8*)&Bs[(j * 16 + l16) * 40 + swz_rd];
            acc[0][j] = __builtin_amdgcn_mfma_f32_16x16x32_bf16(af0, bf, acc[0][j], 0, 0, 0);
            acc[1][j] = __builtin_amdgcn_mfma_f32_16x16x32_bf16(af1, bf, acc[1][j], 0, 0, 0);
        }
    }
#pragma unroll
    for (int j = 0; j < 3; ++j) {
        int col = j * 16 + l16;
        float bb = bias[col];
#pragma unroll
        for (int i = 0; i < 2; ++i) {
#pragma unroll
            for (int r = 0; r < 4; ++r) {
                int row = bm + w * 32 + i * 16 + q * 4 + r;
                if (row < M) {
                    float v = (acc[i][j][r] + bb) * dinv[row];
                    u0[(size_t)row * 48 + col] = __float2half(v);
                }
            }
        }
    }
}

// ---------------- X/Y-split hop: 96B rows, 6 requests/edge, exec-masked tail ----------------
// Theory (r1/r5/r6 fit): hop is TA-request-throughput bound at ~0.7 16B-req/cy/CU.
// Per 32 edges: X0 (edges 0-15 x chunks 0-3), X1 (edges 16-31 x chunks 0-3), Y (edges 0-31 x
// chunks 4-5) -> 192 requests / 32 edges = 6/edge, all useful, all 64 lanes active.
// Tail: per-lane predicated loads -> masked lanes issue ZERO requests (sentinel-select doesn't).

__global__ __launch_bounds__(256) void k_hop(const __half* __restrict__ u, __half* __restrict__ unxt,
                                             const int* __restrict__ rowptr,
                                             const unsigned short* __restrict__ csr,
                                             const float* __restrict__ dinv2, int NT) {
    int n = blockIdx.x * 4 + (threadIdx.x >> 6);
    if (n >= NT) return;
    const int lane = threadIdx.x & 63;
    const int cx = lane & 3;        // X chunk: cols cx*8 .. cx*8+7   (cols 0..31)
    const int jx = lane >> 2;       // X edge slot 0..15
    const int cy = lane & 1;        // Y chunk: cols 32+cy*8 ..       (cols 32..47)
    const int jy = lane >> 1;       // Y edge slot 0..31

    float accX[8] = {0.f, 0.f, 0.f, 0.f, 0.f, 0.f, 0.f, 0.f};
    float accY[8] = {0.f, 0.f, 0.f, 0.f, 0.f, 0.f, 0.f, 0.f};
    const int e0 = rowptr[n], e1 = rowptr[n + 1];
    int e = e0;
    for (; e + 32 <= e1; e += 32) {
        int sx0 = (int)csr[e + jx];
        int sx1 = (int)csr[e + 16 + jx];
        int sy  = (int)csr[e + jy];
        union { uint4 u4; __half2 h2[4]; } gx0, gx1, gy;
        gx0.u4 = *(const uint4*)(u + (size_t)sx0 * 48 + cx * 8);
        gx1.u4 = *(const uint4*)(u + (size_t)sx1 * 48 + cx * 8);
        gy.u4  = *(const uint4*)(u + (size_t)sy  * 48 + 32 + cy * 8);
#pragma unroll
        for (int i = 0; i < 4; ++i) {
            float2 f0 = __half22float2(gx0.h2[i]);
            float2 f1 = __half22float2(gx1.h2[i]);
            float2 fy = __half22float2(gy.h2[i]);
            accX[2 * i]     += f0.x + f1.x;
            accX[2 * i + 1] += f0.y + f1.y;
            accY[2 * i]     += fy.x;
            accY[2 * i + 1] += fy.y;
        }
    }
    if (e < e1) {                                  // masked tail (<32 edges)
        const int rem = e1 - e;
        union { uint4 u4; __half2 h2[4]; } gx0, gx1, gy;
        gx0.u4 = make_uint4(0u, 0u, 0u, 0u);
        gx1.u4 = make_uint4(0u, 0u, 0u, 0u);
        gy.u4  = make_uint4(0u, 0u, 0u, 0u);
        if (jx < rem)      gx0.u4 = *(const uint4*)(u + (size_t)((int)csr[e + jx]) * 48 + cx * 8);
        if (16 + jx < rem) gx1.u4 = *(const uint4*)(u + (size_t)((int)csr[e + 16 + jx]) * 48 + cx * 8);
        if (jy < rem)      gy.u4  = *(const uint4*)(u + (size_t)((int)csr[e + jy]) * 48 + 32 + cy * 8);
#pragma unroll
        for (int i = 0; i < 4; ++i) {
            float2 f0 = __half22float2(gx0.h2[i]);
            float2 f1 = __half22float2(gx1.h2[i]);
            float2 fy = __half22float2(gy.h2[i]);
            accX[2 * i]     += f0.x + f1.x;
            accX[2 * i + 1] += f0.y + f1.y;
            accY[2 * i]     += fy.x;
            accY[2 * i + 1] += fy.y;
        }
    }
    // reduce X over jx (lane bits 2..5), Y over jy (lane bits 1..5)
#pragma unroll
    for (int off = 4; off < 64; off <<= 1) {
#pragma unroll
        for (int i = 0; i < 8; ++i) accX[i] += __shfl_xor(accX[i], off);
    }
#pragma unroll
    for (int off = 2; off < 64; off <<= 1) {
#pragma unroll
        for (int i = 0; i < 8; ++i) accY[i] += __shfl_xor(accY[i], off);
    }
    // writer lane w (0..5) owns chunk w: w<4 -> accX (lane w has cx=w); w>=4 -> accY (lane 4: cy=0, lane 5: cy=1)
    if (lane < 6) {
        float a0 = (lane < 4) ? accX[0] : accY[0];
        float a1 = (lane < 4) ? accX[1] : accY[1];
        float a2 = (lane < 4) ? accX[2] : accY[2];
        float a3 = (lane < 4) ? accX[3] : accY[3];
        float a4 = (lane < 4) ? accX[4] : accY[4];
        float a5 = (lane < 4) ? accX[5] : accY[5];
        float a6 = (lane < 4) ? accX[6] : accY[6];
        float a7 = (lane < 4) ? accX[7] : accY[7];
        union { uint4 u4; __half2 h2[4]; } sv, ov;
        sv.u4 = *(const uint4*)(u + (size_t)n * 48 + lane * 8);   // self-loop term
        float w2 = dinv2[n];
        float2 sf0 = __half22float2(sv.h2[0]);
        float2 sf1 = __half22float2(sv.h2[1]);
        float2 sf2 = __half22float2(sv.h2[2]);
        float2 sf3 = __half22float2(sv.h2[3]);
        float2 r0, r1, r2, r3;
        r0.x = (a0 + sf0.x) * w2;  r0.y = (a1 + sf0.y) * w2;
        r1.x = (a2 + sf1.x) * w2;  r1.y = (a3 + sf1.y) * w2;
        r2.x = (a4 + sf2.x) * w2;  r2.y = (a5 + sf2.y) * w2;
        r3.x = (a6 + sf3.x) * w2;  r3.y = (a7 + sf3.y) * w2;
        ov.h2[0] = __float22half2_rn(r0);
        ov.h2[1] = __float22half2_rn(r1);
        ov.h2[2] = __float22half2_rn(r2);
        ov.h2[3] = __float22half2_rn(r3);
        *(uint4*)(unxt + (size_t)n * 48 + lane * 8) = ov.u4;
    }
}

// ---------------- final: out = log_softmax(sdeg * sum_k temp[k]*u_k), row stride 48 ----------------

__global__ __launch_bounds__(256) void k_final(const __half* __restrict__ u0, const __half* __restrict__ u1,
                                               size_t S, const float* __restrict__ sdeg,
                                               const float* __restrict__ temp,
                                               float* __restrict__ out, int N) {
    int w = (blockIdx.x * 256 + threadIdx.x) >> 6;
    int lane = threadIdx.x & 63;
    if (w >= N) return;
    size_t base = (size_t)w * 48 + lane;
    float val = 0.f, m = -INFINITY;
    if (lane < 48) {
        float acc = temp[0] * __half2float(u0[base]);
        const __half* uk = u1;
#pragma unroll
        for (int k = 1; k <= 10; ++k) {
            acc += temp[k] * __half2float(uk[base]);
            uk += S;
        }
        val = acc * sdeg[w];
        m = val;
    }
#pragma unroll
    for (int off = 32; off; off >>= 1) m = fmaxf(m, __shfl_xor(m, off));
    float ex = (lane < 48) ? __expf(val - m) : 0.f;
    float s = ex;
#pragma unroll
    for (int off = 32; off; off >>= 1) s += __shfl_xor(s, off);
    if (lane < 48) out[(size_t)w * 48 + lane] = val - m - __logf(s);
}

// ---------------- launch ----------------

extern "C" void kernel_launch(void* const* d_in, const int* in_sizes, int n_in,
                              void* d_out, int out_size, void* d_ws, size_t ws_size,
                              hipStream_t stream) {
    const float* x    = (const float*)d_in[0];
    const int*   ei   = (const int*)d_in[1];
    const float* W1   = (const float*)d_in[2];
    const float* b1   = (const float*)d_in[3];
    const float* W2   = (const float*)d_in[4];
    const float* b2   = (const float*)d_in[5];
    const float* temp = (const float*)d_in[6];
    float* out = (float*)d_out;

    const int N = in_sizes[0] / 256;
    const int E = in_sizes[1] / 2;
    const int* src = ei;
    const int* dst = ei + E;

    const int NT  = N + 1;                  // + sentinel node (u rows kept zero)
    const int NT2 = N + 2;
    const int NB  = (NT + BNODES - 1) >> BSH;

    // workspace layout
    char* w8 = (char*)d_ws;
    size_t NP = (size_t)((NT2 + 63) & ~63);
    int*   cnt     = (int*)w8;                          // NP (+128 bktcnt)
    int*   bktcnt  = cnt + NP;                          // 128
    int*   rowptr  = bktcnt + 128;                      // NP
    int*   blk     = rowptr + NP;                       // 256
    float* dinv    = (float*)(blk + 256);               // NP
    float* dinv2   = dinv + NP;                         // NP
    float* sdeg    = dinv2 + NP;                        // NP
    unsigned short* csr = (unsigned short*)(sdeg + NP); // E shorts used (alloc E+32*NT: slack for OOB csr reads)
    size_t csr_i   = (((size_t)E + 32 * NT) / 2 + 32 + 63) & ~(size_t)63;  // ints
    unsigned short* w1t = (unsigned short*)((int*)(sdeg + NP) + csr_i);    // 65536 shorts
    unsigned short* w2t = w1t + 65536;                  // 12288 shorts (+pad)
    unsigned short* xb  = w2t + 12288 + 64;             // N*256 shorts (25.6MB)
    size_t S       = ((size_t)NT * 48 + 127) & ~(size_t)127;  // u-slab stride (halves, 96B rows)
    __half* u0     = (__half*)(xb + (size_t)N * 256);   // S halves
    unsigned short* h1b = (unsigned short*)(u0 + S);    // N*256 shorts (gemm1 out)
    unsigned* stage = (unsigned*)h1b;                   // NB*CAP2 uints ⊂ h1b (dead pre-gemm)
    __half* u1     = (__half*)(h1b + (size_t)N * 256);  // u1..u10 = 10*S halves

    const int nbS = (NT2 + 255) / 256;

    // CSR build
    k_zero  <<<(int)((NP + 128 + 255) / 256), 256, 0, stream>>>(cnt, (int)(NP + 128));
    k_bin   <<<(E + ECHUNK - 1) / ECHUNK, 256, 0, stream>>>(src, dst, bktcnt, stage, E, NB);
    k_cnt   <<<NB, 512, 0, stream>>>(stage, bktcnt, cnt, dinv, dinv2, sdeg, N);
    k_scan1 <<<nbS, 256, 0, stream>>>(cnt, rowptr, blk, NT2);
    k_scan2 <<<1, 256, 0, stream>>>(blk, nbS);
    k_scan3 <<<nbS, 256, 0, stream>>>(rowptr, blk, NT2);
    k_place <<<NB, 512, 0, stream>>>(stage, bktcnt, rowptr, csr, N);

    // casts
    k_castx <<<(N * 256 / 8 + 255) / 256, 256, 0, stream>>>((const float4*)x, (uint4*)xb, N * 256 / 8);
    k_castw <<<(65536 + 12288 + 255) / 256, 256, 0, stream>>>(W1, W2, w1t, w2t);

    // MLP head on MFMA
    dim3 g1((N + 127) / 128, 2);
    k_mgemm1<<<g1, 256, 0, stream>>>(xb, w1t, b1, h1b, N);
    k_mgemm2<<<(N + 127) / 128, 256, 0, stream>>>(h1b, w2t, b2, dinv, u0, N);
    k_zero  <<<1, 64, 0, stream>>>((int*)(u0 + (size_t)N * 48), 24);   // sentinel u0 row (48 halves)

    // K-hop propagation: X/Y-split gather, 6 requests/edge, masked tail
    const int hopBlocks = (NT + 3) / 4;
    for (int k = 0; k < 10; ++k) {
        const __half* cur = (k == 0) ? u0 : (u1 + (size_t)(k - 1) * S);
        __half* nxt = u1 + (size_t)k * S;
        k_hop<<<hopBlocks, 256, 0, stream>>>(cur, nxt, rowptr, csr, dinv2, NT);
    }

    k_final<<<(N + 3) / 4, 256, 0, stream>>>(u0, u1, S, sdeg, temp, out, N);
}

// Round 8
// 614.122 us; speedup vs baseline: 1.0355x; 1.0355x over previous
//
#include <hip/hip_runtime.h>
#include <hip/hip_fp16.h>
#include <math.h>

#define BSH    9          // bucket = 512 nodes
#define BNODES 512
#define NBMAX  128
#define CAP2   24576      // per-bucket stage capacity
#define ECHUNK 6144       // edges per k_bin block

typedef short bf16x8 __attribute__((ext_vector_type(8)));
typedef float f32x4 __attribute__((ext_vector_type(4)));
typedef unsigned u32x4 __attribute__((ext_vector_type(4)));

__device__ __forceinline__ unsigned f2b(float f) {   // float -> bf16 bits, RTN-even
    union { float f; unsigned u; } x; x.f = f;
    return (x.u + 0x7fffu + ((x.u >> 16) & 1u)) >> 16;
}

// ---------------- zero ----------------

__global__ __launch_bounds__(256) void k_zero(int* __restrict__ p, int n) {
    int i = blockIdx.x * 256 + threadIdx.x;
    if (i < n) p[i] = 0;
}

// ---------------- casts ----------------

__global__ __launch_bounds__(256) void k_castx(const float4* __restrict__ x, uint4* __restrict__ xb, int n8) {
    int i = blockIdx.x * 256 + threadIdx.x;
    if (i >= n8) return;
    float4 f0 = x[2 * i], f1 = x[2 * i + 1];
    uint4 o;
    o.x = f2b(f0.x) | (f2b(f0.y) << 16);
    o.y = f2b(f0.z) | (f2b(f0.w) << 16);
    o.z = f2b(f1.x) | (f2b(f1.y) << 16);
    o.w = f2b(f1.z) | (f2b(f1.w) << 16);
    xb[i] = o;
}

// fused: w1t[n*256+k]=bf16(W1[k*256+n]); w2t[n*256+k]=bf16(W2[k*48+n])
__global__ __launch_bounds__(256) void k_castw(const float* __restrict__ W1, const float* __restrict__ W2,
                                               unsigned short* __restrict__ w1t, unsigned short* __restrict__ w2t) {
    int i = blockIdx.x * 256 + threadIdx.x;
    if (i < 65536) {
        int n = i >> 8, k = i & 255;
        w1t[i] = (unsigned short)f2b(W1[k * 256 + n]);
    } else if (i < 65536 + 12288) {
        int j = i - 65536;
        int n = j >> 8, k = j & 255;
        w2t[j] = (unsigned short)f2b(W2[k * 48 + n]);
    }
}

// ---------------- pass 1: block-local binning by dst>>9 ----------------

__global__ __launch_bounds__(256) void k_bin(const int* __restrict__ src, const int* __restrict__ dst,
                                             int* __restrict__ bktcnt, unsigned* __restrict__ stage,
                                             int E, int NB) {
    __shared__ unsigned ecache[ECHUNK];
    __shared__ int lcnt[NBMAX], lbase[NBMAX], lcur[NBMAX];
    const int t = threadIdx.x;
    for (int i = t; i < NBMAX; i += 256) { lcnt[i] = 0; lcur[i] = 0; }
    const int e0 = blockIdx.x * ECHUNK;
    const int m = min(ECHUNK, E - e0);
    __syncthreads();
    for (int i = t; i < m; i += 256) {
        int s = src[e0 + i], d = dst[e0 + i];
        ecache[i] = ((unsigned)d << 16) | (unsigned)s;
        atomicAdd(&lcnt[d >> BSH], 1);
    }
    __syncthreads();
    if (t < NB) lbase[t] = lcnt[t] ? atomicAdd(&bktcnt[t], lcnt[t]) : 0;
    __syncthreads();
    for (int i = t; i < m; i += 256) {
        unsigned p = ecache[i];
        int b = (int)(p >> (16 + BSH));
        int pos = lbase[b] + atomicAdd(&lcur[b], 1);
        if (pos < CAP2) stage[(size_t)b * CAP2 + pos] = p;
    }
}

// ---------------- pass 2a: degrees (total + src<H half) + fused dinv/dinv2/sdeg ----------------

__global__ __launch_bounds__(512) void k_cnt(const unsigned* __restrict__ stage,
                                             const int* __restrict__ bktcnt,
                                             int* __restrict__ cnt, int* __restrict__ cntA,
                                             float* __restrict__ dinv, float* __restrict__ dinv2,
                                             float* __restrict__ sdeg, int N, int H) {
    __shared__ int dcnt[BNODES], dcntA[BNODES];
    const int b = blockIdx.x, t = threadIdx.x;
    dcnt[t] = 0; dcntA[t] = 0;
    __syncthreads();
    const int m = min(bktcnt[b], CAP2);
    const unsigned* st = stage + (size_t)b * CAP2;
    for (int i = t; i < m; i += 512) {
        unsigned p = st[i];
        int dl = (int)((p >> 16) & (BNODES - 1));
        atomicAdd(&dcnt[dl], 1);
        if ((int)(p & 0xffffu) < H) atomicAdd(&dcntA[dl], 1);
    }
    __syncthreads();
    int node = b * BNODES + t;
    if (node <= N) {                       // include sentinel N (deg 0 -> row stays zero)
        int c = dcnt[t];
        cnt[node] = c;
        cntA[node] = dcntA[t];
        float d = (float)c + 1.0f;
        float r = rsqrtf(d);
        dinv[node] = r;
        dinv2[node] = r * r;
        sdeg[node] = d * r;
    }
}

// ---------------- scan over per-half 8-padded row capacities ----------------

__global__ __launch_bounds__(256) void k_scan1(const int* __restrict__ cnt, const int* __restrict__ cntA,
                                               int* __restrict__ rowptr, int* __restrict__ blk, int NT) {
    __shared__ int s[256];
    int t = threadIdx.x, i = blockIdx.x * 256 + t;
    int v = 0;
    if (i < NT) {
        int c = cnt[i], cA = cntA[i];
        v = ((cA + 7) & ~7) + ((c - cA + 7) & ~7);   // A-half and B-half each 8-padded
    }
    s[t] = v; __syncthreads();
#pragma unroll
    for (int off = 1; off < 256; off <<= 1) {
        int x = (t >= off) ? s[t - off] : 0; __syncthreads();
        s[t] += x; __syncthreads();
    }
    if (i < NT) rowptr[i] = s[t] - v;
    if (t == 255) blk[blockIdx.x] = s[255];
}

__global__ __launch_bounds__(256) void k_scan2(int* __restrict__ blk, int nb) {
    __shared__ int s[256];
    int t = threadIdx.x;
    int v = (t < nb) ? blk[t] : 0;
    s[t] = v; __syncthreads();
#pragma unroll
    for (int off = 1; off < 256; off <<= 1) {
        int x = (t >= off) ? s[t - off] : 0; __syncthreads();
        s[t] += x; __syncthreads();
    }
    if (t < nb) blk[t] = s[t] - v;
}

__global__ __launch_bounds__(256) void k_scan3(int* __restrict__ rowptr, int* __restrict__ rowmid,
                                               const int* __restrict__ cntA,
                                               const int* __restrict__ blk, int NT2, int NT) {
    int i = blockIdx.x * 256 + threadIdx.x;
    if (i < NT2) {
        int r = rowptr[i] + blk[blockIdx.x];
        rowptr[i] = r;
        if (i < NT) rowmid[i] = r + ((cntA[i] + 7) & ~7);
    }
}

// ---------------- pass 2b: bidirectional place into CSR (A-half from rowptr, B-half from rowmid) ----------------

__global__ __launch_bounds__(512) void k_place(const unsigned* __restrict__ stage,
                                               const int* __restrict__ bktcnt,
                                               const int* __restrict__ rowptr,
                                               const int* __restrict__ rowmid,
                                               unsigned short* __restrict__ csr, int N, int H) {
    __shared__ int lcurA[BNODES], lcurB[BNODES];
    const int b = blockIdx.x, t = threadIdx.x;
    const int node = b * BNODES + t;
    lcurA[t] = (node < N) ? rowptr[node] : 0;
    lcurB[t] = (node < N) ? rowmid[node] : 0;
    __syncthreads();
    const int m = min(bktcnt[b], CAP2);
    const unsigned* st = stage + (size_t)b * CAP2;
    for (int i = t; i < m; i += 512) {
        unsigned p = st[i];
        int dl = (int)((p >> 16) & (BNODES - 1));
        int s = (int)(p & 0xffffu);
        int pos = (s < H) ? atomicAdd(&lcurA[dl], 1) : atomicAdd(&lcurB[dl], 1);
        csr[pos] = (unsigned short)s;
    }
    __syncthreads();
    if (node < N) {
        int midv = rowmid[node];
        for (int i = lcurA[t]; i < midv; ++i) csr[i] = (unsigned short)N;   // pad A-half
        int e1 = rowptr[node + 1];
        for (int i = lcurB[t]; i < e1; ++i) csr[i] = (unsigned short)N;     // pad B-half
    }
}

// ---------------- MFMA GEMM1: h1b = bf16(relu(xb @ W1 + b1)) ----------------

__global__ __launch_bounds__(256) void k_mgemm1(const unsigned short* __restrict__ xb,
                                                const unsigned short* __restrict__ w1t,
                                                const float* __restrict__ bias,
                                                unsigned short* __restrict__ h1b, int M) {
    __shared__ unsigned short sbuf[128 * 136];
    unsigned short* As = sbuf;
    unsigned short* Bs = sbuf + 128 * 40;
    const int t = threadIdx.x;
    const int bm = blockIdx.x * 128;
    const int bn = blockIdx.y * 128;
    const int w = t >> 6, lane = t & 63;
    const int q = lane >> 4, l16 = lane & 15;

    f32x4 acc[2][8] = {};
    const int ar0 = t >> 2;
    const int kc  = t & 3;
    const int swz_st = ((kc ^ (ar0 & 3)) * 8);
    int gr0 = bm + ar0;       if (gr0 >= M) gr0 = M - 1;
    int gr1 = bm + ar0 + 64;  if (gr1 >= M) gr1 = M - 1;
    const int swz_rd = (q ^ (l16 & 3)) * 8;

    for (int k0 = 0; k0 < 256; k0 += 32) {
        uint4 a0 = *(const uint4*)&xb[(size_t)gr0 * 256 + k0 + kc * 8];
        uint4 a1 = *(const uint4*)&xb[(size_t)gr1 * 256 + k0 + kc * 8];
        uint4 b0 = *(const uint4*)&w1t[(size_t)(bn + ar0) * 256 + k0 + kc * 8];
        uint4 b1 = *(const uint4*)&w1t[(size_t)(bn + ar0 + 64) * 256 + k0 + kc * 8];
        __syncthreads();
        *(uint4*)&As[ar0 * 40 + swz_st] = a0;
        *(uint4*)&As[(ar0 + 64) * 40 + swz_st] = a1;
        *(uint4*)&Bs[ar0 * 40 + swz_st] = b0;
        *(uint4*)&Bs[(ar0 + 64) * 40 + swz_st] = b1;
        __syncthreads();
        bf16x8 af0 = *(bf16x8*)&As[(w * 32 + l16) * 40 + swz_rd];
        bf16x8 af1 = *(bf16x8*)&As[(w * 32 + 16 + l16) * 40 + swz_rd];
#pragma unroll
        for (int j = 0; j < 8; ++j) {
            bf16x8 bf = *(bf16x8*)&Bs[(j * 16 + l16) * 40 + swz_rd];
            acc[0][j] = __builtin_amdgcn_mfma_f32_16x16x32_bf16(af0, bf, acc[0][j], 0, 0, 0);
            acc[1][j] = __builtin_amdgcn_mfma_f32_16x16x32_bf16(af1, bf, acc[1][j], 0, 0, 0);
        }
    }
    __syncthreads();
#pragma unroll
    for (int j = 0; j < 8; ++j) {
        int col = j * 16 + l16;
        float bb = bias[bn + col];
#pragma unroll
        for (int i = 0; i < 2; ++i) {
#pragma unroll
            for (int r = 0; r < 4; ++r) {
                float v = fmaxf(acc[i][j][r] + bb, 0.f);
                sbuf[(w * 32 + i * 16 + q * 4 + r) * 136 + col] = (unsigned short)f2b(v);
            }
        }
    }
    __syncthreads();
    const int row = t >> 1;
    const int ch = (t & 1) * 64;
    if (bm + row < M) {
#pragma unroll
        for (int i = 0; i < 8; ++i) {
            uint4 v = *(uint4*)&sbuf[row * 136 + ch + i * 8];
            *(uint4*)&h1b[(size_t)(bm + row) * 256 + bn + ch + i * 8] = v;
        }
    }
}

// ---------------- MFMA GEMM2: u0 = fp16(dinv .* (h1b @ W2 + b2)), row stride 64 halves ----------------

__global__ __launch_bounds__(256) void k_mgemm2(const unsigned short* __restrict__ h1b,
                                                const unsigned short* __restrict__ w2t,
                                                const float* __restrict__ bias,
                                                const float* __restrict__ dinv,
                                                __half* __restrict__ u0, int M) {
    __shared__ unsigned short As[128 * 40];
    __shared__ unsigned short Bs[48 * 40];
    const int t = threadIdx.x;
    const int bm = blockIdx.x * 128;
    const int w = t >> 6, lane = t & 63;
    const int q = lane >> 4, l16 = lane & 15;

    f32x4 acc[2][3] = {};
    const int ar0 = t >> 2;
    const int kc  = t & 3;
    const int swz_st = ((kc ^ (ar0 & 3)) * 8);
    int gr0 = bm + ar0;      if (gr0 >= M) gr0 = M - 1;
    int gr1 = bm + ar0 + 64; if (gr1 >= M) gr1 = M - 1;
    const int swz_rd = (q ^ (l16 & 3)) * 8;

    for (int k0 = 0; k0 < 256; k0 += 32) {
        uint4 a0 = *(const uint4*)&h1b[(size_t)gr0 * 256 + k0 + kc * 8];
        uint4 a1 = *(const uint4*)&h1b[(size_t)gr1 * 256 + k0 + kc * 8];
        uint4 bv;
        if (t < 192) bv = *(const uint4*)&w2t[(size_t)ar0 * 256 + k0 + kc * 8];
        __syncthreads();
        *(uint4*)&As[ar0 * 40 + swz_st] = a0;
        *(uint4*)&As[(ar0 + 64) * 40 + swz_st] = a1;
        if (t < 192) *(uint4*)&Bs[ar0 * 40 + swz_st] = bv;
        __syncthreads();
        bf16x8 af0 = *(bf16x8*)&As[(w * 32 + l16) * 40 + swz_rd];
        bf16x8 af1 = *(bf16x8*)&As[(w * 32 + 16 + l16) * 40 + swz_rd];
#pragma unroll
        for (int j = 0; j < 3; ++j) {
            bf16x8 bf = *(bf16x8*)&Bs[(j * 16 + l16) * 40 + swz_rd];
            acc[0][j] = __builtin_amdgcn_mfma_f32_16x16x32_bf16(af0, bf, acc[0][j], 0, 0, 0);
            acc[1][j] = __builtin_amdgcn_mfma_f32_16x16x32_bf16(af1, bf, acc[1][j], 0, 0, 0);
        }
    }
#pragma unroll
    for (int j = 0; j < 3; ++j) {
        int col = j * 16 + l16;
        float bb = bias[col];
#pragma unroll
        for (int i = 0; i < 2; ++i) {
#pragma unroll
            for (int r = 0; r < 4; ++r) {
                int row = bm + w * 32 + i * 16 + q * 4 + r;
                if (row < M) {
                    float v = (acc[i][j][r] + bb) * dinv[row];
                    u0[(size_t)row * 64 + col] = __float2half(v);
                }
            }
        }
    }
}

// ---------------- src-partitioned hop (2 passes): per-pass gather slice fits 4MB per-XCD L2 ----------------
// r7 counters: FETCH 42.7MB/hop = L2 capacity thrash (table > 4MB/XCD). Pass A gathers only rows
// [0,H) (3.2MB slice), pass B rows [H,N). r5-proven structure kept: 128B rows, lane=j*8+c quad-merge,
// 8 rows/gather-instruction (r7 lesson: wider divergence serializes), 4 groups in flight,
// sentinel-masked groups (r6-proven free). Pass A writes fp16 partial (NT store, no L2 pollution);
// pass B adds partial + self, scales.

__global__ __launch_bounds__(256) void k_hop(const __half* __restrict__ u, __half* __restrict__ unxt,
                                             const int* __restrict__ starts, const int* __restrict__ ends,
                                             const unsigned short* __restrict__ csr,
                                             const float* __restrict__ dinv2, int NT, int N, int fin) {
    int n = blockIdx.x * 4 + (threadIdx.x >> 6);
    if (n >= NT) return;
    const int lane = threadIdx.x & 63;
    const int c = lane & 7;         // chunk of 8 halves (0..5 useful, 6..7 row pad)
    const int j = lane >> 3;        // edge slot 0..7

    float acc[8] = {0.f, 0.f, 0.f, 0.f, 0.f, 0.f, 0.f, 0.f};
    const int e0 = starts[n], e1 = ends[n];
    for (int e = e0; e < e1; e += 32) {
        const int rem = e1 - e;                     // multiple of 8, > 0
        int t0 = (int)csr[e + j];
        int t1 = (int)csr[e + 8 + j];
        int t2 = (int)csr[e + 16 + j];
        int t3 = (int)csr[e + 24 + j];
        int s0 = t0;
        int s1 = (rem > 8)  ? t1 : N;
        int s2 = (rem > 16) ? t2 : N;
        int s3 = (rem > 24) ? t3 : N;
        union { uint4 u4; __half2 h2[4]; } g0, g1, g2, g3;
        g0.u4 = *(const uint4*)(u + (size_t)s0 * 64 + c * 8);
        g1.u4 = *(const uint4*)(u + (size_t)s1 * 64 + c * 8);
        g2.u4 = *(const uint4*)(u + (size_t)s2 * 64 + c * 8);
        g3.u4 = *(const uint4*)(u + (size_t)s3 * 64 + c * 8);
#pragma unroll
        for (int i = 0; i < 4; ++i) {
            __half2 p  = __hadd2(g0.h2[i], g1.h2[i]);   // sentinel rows are exact zero
            __half2 qq = __hadd2(g2.h2[i], g3.h2[i]);
            float2 fp = __half22float2(p);
            float2 fq = __half22float2(qq);
            acc[2 * i]     += fp.x + fq.x;
            acc[2 * i + 1] += fp.y + fq.y;
        }
    }
    // reduce over edge slots j (lanes 8 apart, same chunk c)
#pragma unroll
    for (int off = 8; off < 64; off <<= 1) {
#pragma unroll
        for (int i = 0; i < 8; ++i) acc[i] += __shfl_xor(acc[i], off);
    }
    if (j == 0 && c < 6) {
        union { u32x4 v; __half2 h2[4]; } ov;
        if (fin) {
            union { uint4 u4; __half2 h2[4]; } sv, pv;
            sv.u4 = *(const uint4*)(u + (size_t)n * 64 + c * 8);      // self-loop term
            pv.u4 = *(const uint4*)(unxt + (size_t)n * 64 + c * 8);   // pass-A partial
            float w2 = dinv2[n];
#pragma unroll
            for (int i = 0; i < 4; ++i) {
                float2 sf = __half22float2(sv.h2[i]);
                float2 pf = __half22float2(pv.h2[i]);
                float2 r;
                r.x = (acc[2 * i]     + pf.x + sf.x) * w2;
                r.y = (acc[2 * i + 1] + pf.y + sf.y) * w2;
                ov.h2[i] = __float22half2_rn(r);
            }
        } else {
#pragma unroll
            for (int i = 0; i < 4; ++i) {
                float2 r;
                r.x = acc[2 * i];
                r.y = acc[2 * i + 1];
                ov.h2[i] = __float22half2_rn(r);
            }
        }
        __builtin_nontemporal_store(ov.v, (u32x4*)(unxt + (size_t)n * 64 + c * 8));
    }
}

// ---------------- final: out = log_softmax(sdeg * sum_k temp[k]*u_k), row stride 64 ----------------

__global__ __launch_bounds__(256) void k_final(const __half* __restrict__ u0, const __half* __restrict__ u1,
                                               size_t S, const float* __restrict__ sdeg,
                                               const float* __restrict__ temp,
                                               float* __restrict__ out, int N) {
    int w = (blockIdx.x * 256 + threadIdx.x) >> 6;
    int lane = threadIdx.x & 63;
    if (w >= N) return;
    size_t base = (size_t)w * 64 + lane;
    float val = 0.f, m = -INFINITY;
    if (lane < 48) {
        float acc = temp[0] * __half2float(u0[base]);
        const __half* uk = u1;
#pragma unroll
        for (int k = 1; k <= 10; ++k) {
            acc += temp[k] * __half2float(uk[base]);
            uk += S;
        }
        val = acc * sdeg[w];
        m = val;
    }
#pragma unroll
    for (int off = 32; off; off >>= 1) m = fmaxf(m, __shfl_xor(m, off));
    float ex = (lane < 48) ? __expf(val - m) : 0.f;
    float s = ex;
#pragma unroll
    for (int off = 32; off; off >>= 1) s += __shfl_xor(s, off);
    if (lane < 48) out[(size_t)w * 48 + lane] = val - m - __logf(s);
}

// ---------------- launch ----------------

extern "C" void kernel_launch(void* const* d_in, const int* in_sizes, int n_in,
                              void* d_out, int out_size, void* d_ws, size_t ws_size,
                              hipStream_t stream) {
    const float* x    = (const float*)d_in[0];
    const int*   ei   = (const int*)d_in[1];
    const float* W1   = (const float*)d_in[2];
    const float* b1   = (const float*)d_in[3];
    const float* W2   = (const float*)d_in[4];
    const float* b2   = (const float*)d_in[5];
    const float* temp = (const float*)d_in[6];
    float* out = (float*)d_out;

    const int N = in_sizes[0] / 256;
    const int E = in_sizes[1] / 2;
    const int* src = ei;
    const int* dst = ei + E;

    const int NT  = N + 1;                  // + sentinel node (u rows kept zero)
    const int NT2 = N + 2;
    const int NB  = (NT + BNODES - 1) >> BSH;
    const int H   = N / 2;                  // src-partition split: slice = H*128B = 3.2MB < 4MB/XCD L2

    // workspace layout
    char* w8 = (char*)d_ws;
    size_t NP = (size_t)((NT2 + 63) & ~63);
    int*   cnt     = (int*)w8;                          // NP
    int*   cntA    = cnt + NP;                          // NP
    int*   bktcnt  = cntA + NP;                         // 128
    int*   rowptr  = bktcnt + 128;                      // NP
    int*   rowmid  = rowptr + NP;                       // NP
    int*   blk     = rowmid + NP;                       // 256
    float* dinv    = (float*)(blk + 256);               // NP
    float* dinv2   = dinv + NP;                         // NP
    float* sdeg    = dinv2 + NP;                        // NP
    unsigned short* csr = (unsigned short*)(sdeg + NP); // <= E + 14*NT shorts used (alloc E+32*NT: slack)
    size_t csr_i   = (((size_t)E + 32 * NT) / 2 + 32 + 63) & ~(size_t)63;  // ints
    unsigned short* w1t = (unsigned short*)((int*)(sdeg + NP) + csr_i);    // 65536 shorts
    unsigned short* w2t = w1t + 65536;                  // 12288 shorts (+pad)
    unsigned short* xb  = w2t + 12288 + 64;             // N*256 shorts (25.6MB)
    size_t S       = ((size_t)NT * 64 + 127) & ~(size_t)127;  // u-slab stride (halves, 128B rows)
    __half* u0     = (__half*)(xb + (size_t)N * 256);   // S halves
    unsigned short* h1b = (unsigned short*)(u0 + S);    // N*256 shorts (gemm1 out)
    unsigned* stage = (unsigned*)h1b;                   // NB*CAP2 uints ⊂ h1b (dead pre-gemm)
    __half* u1     = (__half*)(h1b + (size_t)N * 256);  // u1..u10 = 10*S halves

    const int nbS = (NT2 + 255) / 256;

    // CSR build (bidirectional: A-half src<H from rowptr, B-half from rowmid)
    k_zero  <<<(int)((2 * NP + 128 + 255) / 256), 256, 0, stream>>>(cnt, (int)(2 * NP + 128));
    k_bin   <<<(E + ECHUNK - 1) / ECHUNK, 256, 0, stream>>>(src, dst, bktcnt, stage, E, NB);
    k_cnt   <<<NB, 512, 0, stream>>>(stage, bktcnt, cnt, cntA, dinv, dinv2, sdeg, N, H);
    k_scan1 <<<nbS, 256, 0, stream>>>(cnt, cntA, rowptr, blk, NT2);
    k_scan2 <<<1, 256, 0, stream>>>(blk, nbS);
    k_scan3 <<<nbS, 256, 0, stream>>>(rowptr, rowmid, cntA, blk, NT2, NT);
    k_place <<<NB, 512, 0, stream>>>(stage, bktcnt, rowptr, rowmid, csr, N, H);

    // casts
    k_castx <<<(N * 256 / 8 + 255) / 256, 256, 0, stream>>>((const float4*)x, (uint4*)xb, N * 256 / 8);
    k_castw <<<(65536 + 12288 + 255) / 256, 256, 0, stream>>>(W1, W2, w1t, w2t);

    // MLP head on MFMA
    dim3 g1((N + 127) / 128, 2);
    k_mgemm1<<<g1, 256, 0, stream>>>(xb, w1t, b1, h1b, N);
    k_mgemm2<<<(N + 127) / 128, 256, 0, stream>>>(h1b, w2t, b2, dinv, u0, N);
    k_zero  <<<1, 64, 0, stream>>>((int*)(u0 + (size_t)N * 64), 24);   // sentinel u0 row (cols 0..47)

    // K-hop propagation: 2 src-partitioned passes per hop (each pass's slice L2-resident)
    const int hopBlocks = (NT + 3) / 4;
    for (int k = 0; k < 10; ++k) {
        const __half* cur = (k == 0) ? u0 : (u1 + (size_t)(k - 1) * S);
        __half* nxt = u1 + (size_t)k * S;
        k_hop<<<hopBlocks, 256, 0, stream>>>(cur, nxt, rowptr, rowmid, csr, dinv2, NT, N, 0);
        k_hop<<<hopBlocks, 256, 0, stream>>>(cur, nxt, rowmid, rowptr + 1, csr, dinv2, NT, N, 1);
    }

    k_final<<<(N + 3) / 4, 256, 0, stream>>>(u0, u1, S, sdeg, temp, out, N);
}

// Round 10
// 541.094 us; speedup vs baseline: 1.1752x; 1.1350x over previous
//
#include <hip/hip_runtime.h>
#include <hip/hip_fp16.h>
#include <math.h>

#define BSH    9          // bucket = 512 nodes
#define BNODES 512
#define NBMAX  128
#define CAP2   24576      // per-bucket stage capacity
#define ECHUNK 6144       // edges per k_bin block

typedef short bf16x8 __attribute__((ext_vector_type(8)));
typedef float f32x4 __attribute__((ext_vector_type(4)));

__device__ __forceinline__ unsigned f2b(float f) {   // float -> bf16 bits, RTN-even
    union { float f; unsigned u; } x; x.f = f;
    return (x.u + 0x7fffu + ((x.u >> 16) & 1u)) >> 16;
}

// ---------------- zero ----------------

__global__ __launch_bounds__(256) void k_zero(int* __restrict__ p, int n) {
    int i = blockIdx.x * 256 + threadIdx.x;
    if (i < n) p[i] = 0;
}

// ---------------- casts ----------------

__global__ __launch_bounds__(256) void k_castx(const float4* __restrict__ x, uint4* __restrict__ xb, int n8) {
    int i = blockIdx.x * 256 + threadIdx.x;
    if (i >= n8) return;
    float4 f0 = x[2 * i], f1 = x[2 * i + 1];
    uint4 o;
    o.x = f2b(f0.x) | (f2b(f0.y) << 16);
    o.y = f2b(f0.z) | (f2b(f0.w) << 16);
    o.z = f2b(f1.x) | (f2b(f1.y) << 16);
    o.w = f2b(f1.z) | (f2b(f1.w) << 16);
    xb[i] = o;
}

// fused: w1t[n*256+k]=bf16(W1[k*256+n]); w2t[n*256+k]=bf16(W2[k*48+n])
__global__ __launch_bounds__(256) void k_castw(const float* __restrict__ W1, const float* __restrict__ W2,
                                               unsigned short* __restrict__ w1t, unsigned short* __restrict__ w2t) {
    int i = blockIdx.x * 256 + threadIdx.x;
    if (i < 65536) {
        int n = i >> 8, k = i & 255;
        w1t[i] = (unsigned short)f2b(W1[k * 256 + n]);
    } else if (i < 65536 + 12288) {
        int j = i - 65536;
        int n = j >> 8, k = j & 255;
        w2t[j] = (unsigned short)f2b(W2[k * 48 + n]);
    }
}

// ---------------- pass 1: block-local binning by dst>>9 ----------------

__global__ __launch_bounds__(256) void k_bin(const int* __restrict__ src, const int* __restrict__ dst,
                                             int* __restrict__ bktcnt, unsigned* __restrict__ stage,
                                             int E, int NB) {
    __shared__ unsigned ecache[ECHUNK];
    __shared__ int lcnt[NBMAX], lbase[NBMAX], lcur[NBMAX];
    const int t = threadIdx.x;
    for (int i = t; i < NBMAX; i += 256) { lcnt[i] = 0; lcur[i] = 0; }
    const int e0 = blockIdx.x * ECHUNK;
    const int m = min(ECHUNK, E - e0);
    __syncthreads();
    for (int i = t; i < m; i += 256) {
        int s = src[e0 + i], d = dst[e0 + i];
        ecache[i] = ((unsigned)d << 16) | (unsigned)s;
        atomicAdd(&lcnt[d >> BSH], 1);
    }
    __syncthreads();
    if (t < NB) lbase[t] = lcnt[t] ? atomicAdd(&bktcnt[t], lcnt[t]) : 0;
    __syncthreads();
    for (int i = t; i < m; i += 256) {
        unsigned p = ecache[i];
        int b = (int)(p >> (16 + BSH));
        int pos = lbase[b] + atomicAdd(&lcur[b], 1);
        if (pos < CAP2) stage[(size_t)b * CAP2 + pos] = p;
    }
}

// ---------------- pass 2a: degrees per bucket + fused dinv/dinv2/sdeg ----------------

__global__ __launch_bounds__(512) void k_cnt(const unsigned* __restrict__ stage,
                                             const int* __restrict__ bktcnt,
                                             int* __restrict__ cnt,
                                             float* __restrict__ dinv, float* __restrict__ dinv2,
                                             float* __restrict__ sdeg, int N) {
    __shared__ int dcnt[BNODES];
    const int b = blockIdx.x, t = threadIdx.x;
    dcnt[t] = 0;
    __syncthreads();
    const int m = min(bktcnt[b], CAP2);
    const unsigned* st = stage + (size_t)b * CAP2;
    for (int i = t; i < m; i += 512)
        atomicAdd(&dcnt[(st[i] >> 16) & (BNODES - 1)], 1);
    __syncthreads();
    int node = b * BNODES + t;
    if (node <= N) {                       // include sentinel N (deg 0 -> row stays zero)
        int c = dcnt[t];
        cnt[node] = c;
        float d = (float)c + 1.0f;
        float r = rsqrtf(d);
        dinv[node] = r;
        dinv2[node] = r * r;
        sdeg[node] = d * r;
    }
}

// ---------------- scan over 8-padded row capacities ----------------

__global__ __launch_bounds__(256) void k_scan1(const int* __restrict__ cnt, int* __restrict__ rowptr,
                                               int* __restrict__ blk, int NT) {
    __shared__ int s[256];
    int t = threadIdx.x, i = blockIdx.x * 256 + t;
    int v = (i < NT) ? ((cnt[i] + 7) & ~7) : 0;   // pad rows to multiple of 8 (r2-proven)
    s[t] = v; __syncthreads();
#pragma unroll
    for (int off = 1; off < 256; off <<= 1) {
        int x = (t >= off) ? s[t - off] : 0; __syncthreads();
        s[t] += x; __syncthreads();
    }
    if (i < NT) rowptr[i] = s[t] - v;
    if (t == 255) blk[blockIdx.x] = s[255];
}

__global__ __launch_bounds__(256) void k_scan2(int* __restrict__ blk, int nb) {
    __shared__ int s[256];
    int t = threadIdx.x;
    int v = (t < nb) ? blk[t] : 0;
    s[t] = v; __syncthreads();
#pragma unroll
    for (int off = 1; off < 256; off <<= 1) {
        int x = (t >= off) ? s[t - off] : 0; __syncthreads();
        s[t] += x; __syncthreads();
    }
    if (t < nb) blk[t] = s[t] - v;
}

__global__ __launch_bounds__(256) void k_scan3(int* __restrict__ rowptr, const int* __restrict__ blk, int NT) {
    int i = blockIdx.x * 256 + threadIdx.x;
    if (i < NT) rowptr[i] += blk[blockIdx.x];
}

// ---------------- pass 2b: place into CSR (ushort) + pad ----------------

__global__ __launch_bounds__(512) void k_place(const unsigned* __restrict__ stage,
                                               const int* __restrict__ bktcnt,
                                               const int* __restrict__ rowptr,
                                               unsigned short* __restrict__ csr, int N) {
    __shared__ int lcur[BNODES];
    const int b = blockIdx.x, t = threadIdx.x;
    const int node = b * BNODES + t;
    lcur[t] = (node < N) ? rowptr[node] : 0;
    __syncthreads();
    const int m = min(bktcnt[b], CAP2);
    const unsigned* st = stage + (size_t)b * CAP2;
    for (int i = t; i < m; i += 512) {
        unsigned p = st[i];
        int dl = (int)((p >> 16) & (BNODES - 1));
        int pos = atomicAdd(&lcur[dl], 1);
        csr[pos] = (unsigned short)(p & 0xffffu);
    }
    __syncthreads();
    if (node < N) {
        int e1 = rowptr[node + 1];
        for (int i = lcur[t]; i < e1; ++i) csr[i] = (unsigned short)N;
    }
}

// ---------------- MFMA GEMM1: h1b = bf16(relu(xb @ W1 + b1)) ----------------

__global__ __launch_bounds__(256) void k_mgemm1(const unsigned short* __restrict__ xb,
                                                const unsigned short* __restrict__ w1t,
                                                const float* __restrict__ bias,
                                                unsigned short* __restrict__ h1b, int M) {
    __shared__ unsigned short sbuf[128 * 136];
    unsigned short* As = sbuf;
    unsigned short* Bs = sbuf + 128 * 40;
    const int t = threadIdx.x;
    const int bm = blockIdx.x * 128;
    const int bn = blockIdx.y * 128;
    const int w = t >> 6, lane = t & 63;
    const int q = lane >> 4, l16 = lane & 15;

    f32x4 acc[2][8] = {};
    const int ar0 = t >> 2;
    const int kc  = t & 3;
    const int swz_st = ((kc ^ (ar0 & 3)) * 8);
    int gr0 = bm + ar0;       if (gr0 >= M) gr0 = M - 1;
    int gr1 = bm + ar0 + 64;  if (gr1 >= M) gr1 = M - 1;
    const int swz_rd = (q ^ (l16 & 3)) * 8;

    for (int k0 = 0; k0 < 256; k0 += 32) {
        uint4 a0 = *(const uint4*)&xb[(size_t)gr0 * 256 + k0 + kc * 8];
        uint4 a1 = *(const uint4*)&xb[(size_t)gr1 * 256 + k0 + kc * 8];
        uint4 b0 = *(const uint4*)&w1t[(size_t)(bn + ar0) * 256 + k0 + kc * 8];
        uint4 b1 = *(const uint4*)&w1t[(size_t)(bn + ar0 + 64) * 256 + k0 + kc * 8];
        __syncthreads();
        *(uint4*)&As[ar0 * 40 + swz_st] = a0;
        *(uint4*)&As[(ar0 + 64) * 40 + swz_st] = a1;
        *(uint4*)&Bs[ar0 * 40 + swz_st] = b0;
        *(uint4*)&Bs[(ar0 + 64) * 40 + swz_st] = b1;
        __syncthreads();
        bf16x8 af0 = *(bf16x8*)&As[(w * 32 + l16) * 40 + swz_rd];
        bf16x8 af1 = *(bf16x8*)&As[(w * 32 + 16 + l16) * 40 + swz_rd];
#pragma unroll
        for (int j = 0; j < 8; ++j) {
            bf16x8 bf = *(bf16x8*)&Bs[(j * 16 + l16) * 40 + swz_rd];
            acc[0][j] = __builtin_amdgcn_mfma_f32_16x16x32_bf16(af0, bf, acc[0][j], 0, 0, 0);
            acc[1][j] = __builtin_amdgcn_mfma_f32_16x16x32_bf16(af1, bf, acc[1][j], 0, 0, 0);
        }
    }
    __syncthreads();
#pragma unroll
    for (int j = 0; j < 8; ++j) {
        int col = j * 16 + l16;
        float bb = bias[bn + col];
#pragma unroll
        for (int i = 0; i < 2; ++i) {
#pragma unroll
            for (int r = 0; r < 4; ++r) {
                float v = fmaxf(acc[i][j][r] + bb, 0.f);
                sbuf[(w * 32 + i * 16 + q * 4 + r) * 136 + col] = (unsigned short)f2b(v);
            }
        }
    }
    __syncthreads();
    const int row = t >> 1;
    const int ch = (t & 1) * 64;
    if (bm + row < M) {
#pragma unroll
        for (int i = 0; i < 8; ++i) {
            uint4 v = *(uint4*)&sbuf[row * 136 + ch + i * 8];
            *(uint4*)&h1b[(size_t)(bm + row) * 256 + bn + ch + i * 8] = v;
        }
    }
}

// ---------------- MFMA GEMM2: u0 = fp16(dinv .* (h1b @ W2 + b2)), row stride 64 halves ----------------

__global__ __launch_bounds__(256) void k_mgemm2(const unsigned short* __restrict__ h1b,
                                                const unsigned short* __restrict__ w2t,
                                                const float* __restrict__ bias,
                                                const float* __restrict__ dinv,
                                                __half* __restrict__ u0, int M) {
    __shared__ unsigned short As[128 * 40];
    __shared__ unsigned short Bs[48 * 40];
    const int t = threadIdx.x;
    const int bm = blockIdx.x * 128;
    const int w = t >> 6, lane = t & 63;
    const int q = lane >> 4, l16 = lane & 15;

    f32x4 acc[2][3] = {};
    const int ar0 = t >> 2;
    const int kc  = t & 3;
    const int swz_st = ((kc ^ (ar0 & 3)) * 8);
    int gr0 = bm + ar0;      if (gr0 >= M) gr0 = M - 1;
    int gr1 = bm + ar0 + 64; if (gr1 >= M) gr1 = M - 1;
    const int swz_rd = (q ^ (l16 & 3)) * 8;

    for (int k0 = 0; k0 < 256; k0 += 32) {
        uint4 a0 = *(const uint4*)&h1b[(size_t)gr0 * 256 + k0 + kc * 8];
        uint4 a1 = *(const uint4*)&h1b[(size_t)gr1 * 256 + k0 + kc * 8];
        uint4 bv;
        if (t < 192) bv = *(const uint4*)&w2t[(size_t)ar0 * 256 + k0 + kc * 8];
        __syncthreads();
        *(uint4*)&As[ar0 * 40 + swz_st] = a0;
        *(uint4*)&As[(ar0 + 64) * 40 + swz_st] = a1;
        if (t < 192) *(uint4*)&Bs[ar0 * 40 + swz_st] = bv;
        __syncthreads();
        bf16x8 af0 = *(bf16x8*)&As[(w * 32 + l16) * 40 + swz_rd];
        bf16x8 af1 = *(bf16x8*)&As[(w * 32 + 16 + l16) * 40 + swz_rd];
#pragma unroll
        for (int j = 0; j < 3; ++j) {
            bf16x8 bf = *(bf16x8*)&Bs[(j * 16 + l16) * 40 + swz_rd];
            acc[0][j] = __builtin_amdgcn_mfma_f32_16x16x32_bf16(af0, bf, acc[0][j], 0, 0, 0);
            acc[1][j] = __builtin_amdgcn_mfma_f32_16x16x32_bf16(af1, bf, acc[1][j], 0, 0, 0);
        }
    }
#pragma unroll
    for (int j = 0; j < 3; ++j) {
        int col = j * 16 + l16;
        float bb = bias[col];
#pragma unroll
        for (int i = 0; i < 2; ++i) {
#pragma unroll
            for (int r = 0; r < 4; ++r) {
                int row = bm + w * 32 + i * 16 + q * 4 + r;
                if (row < M) {
                    float v = (acc[i][j][r] + bb) * dinv[row];
                    u0[(size_t)row * 64 + col] = __float2half(v);
                }
            }
        }
    }
}

// ---------------- hop fp16->fp16 (r5-proven 33us structure): 128B rows, lane=j*8+c, 32+8 ----------------

__global__ __launch_bounds__(256) void k_hop16(const __half* __restrict__ u, __half* __restrict__ unxt,
                                               const int* __restrict__ rowptr,
                                               const unsigned short* __restrict__ csr,
                                               const float* __restrict__ dinv2, int NT) {
    int n = blockIdx.x * 4 + (threadIdx.x >> 6);
    if (n >= NT) return;
    const int lane = threadIdx.x & 63;
    const int c = lane & 7;
    const int j = lane >> 3;

    float acc[8] = {0.f, 0.f, 0.f, 0.f, 0.f, 0.f, 0.f, 0.f};
    const int e0 = rowptr[n], e1 = rowptr[n + 1];
    int e = e0;
    for (; e + 32 <= e1; e += 32) {
        int sa = (int)csr[e + j];
        int sb = (int)csr[e + 8 + j];
        int sc = (int)csr[e + 16 + j];
        int sd = (int)csr[e + 24 + j];
        union { uint4 u4; __half2 h2[4]; } ga, gb, gc, gd;
        ga.u4 = *(const uint4*)(u + (size_t)sa * 64 + c * 8);
        gb.u4 = *(const uint4*)(u + (size_t)sb * 64 + c * 8);
        gc.u4 = *(const uint4*)(u + (size_t)sc * 64 + c * 8);
        gd.u4 = *(const uint4*)(u + (size_t)sd * 64 + c * 8);
#pragma unroll
        for (int i = 0; i < 4; ++i) {
            __half2 p = __hadd2(ga.h2[i], gb.h2[i]);
            __half2 qq = __hadd2(gc.h2[i], gd.h2[i]);
            float2 fp = __half22float2(p);
            float2 fq = __half22float2(qq);
            acc[2 * i]     += fp.x + fq.x;
            acc[2 * i + 1] += fp.y + fq.y;
        }
    }
    for (; e < e1; e += 8) {
        int sa = (int)csr[e + j];
        union { uint4 u4; __half2 h2[4]; } ga;
        ga.u4 = *(const uint4*)(u + (size_t)sa * 64 + c * 8);
#pragma unroll
        for (int i = 0; i < 4; ++i) {
            float2 fa = __half22float2(ga.h2[i]);
            acc[2 * i]     += fa.x;
            acc[2 * i + 1] += fa.y;
        }
    }
#pragma unroll
    for (int off = 8; off < 64; off <<= 1) {
#pragma unroll
        for (int i = 0; i < 8; ++i) acc[i] += __shfl_xor(acc[i], off);
    }
    if (j == 0 && c < 6) {
        union { uint4 u4; __half2 h2[4]; } sv, ov;
        sv.u4 = *(const uint4*)(u + (size_t)n * 64 + c * 8);
        float w2 = dinv2[n];
#pragma unroll
        for (int i = 0; i < 4; ++i) {
            float2 sf = __half22float2(sv.h2[i]);
            float2 r;
            r.x = (acc[2 * i]     + sf.x) * w2;
            r.y = (acc[2 * i + 1] + sf.y) * w2;
            ov.h2[i] = __float22half2_rn(r);
        }
        *(uint4*)(unxt + (size_t)n * 64 + c * 8) = ov.u4;
    }
}

// ---------------- hop fp16->fp8: r5 gather, epilogue packs fp8 e4m3 into 64B rows ----------------

__global__ __launch_bounds__(256) void k_hopm(const __half* __restrict__ u, unsigned char* __restrict__ un8,
                                              const int* __restrict__ rowptr,
                                              const unsigned short* __restrict__ csr,
                                              const float* __restrict__ dinv2, int NT) {
    int n = blockIdx.x * 4 + (threadIdx.x >> 6);
    if (n >= NT) return;
    const int lane = threadIdx.x & 63;
    const int c = lane & 7;
    const int j = lane >> 3;

    float acc[8] = {0.f, 0.f, 0.f, 0.f, 0.f, 0.f, 0.f, 0.f};
    const int e0 = rowptr[n], e1 = rowptr[n + 1];
    int e = e0;
    for (; e + 32 <= e1; e += 32) {
        int sa = (int)csr[e + j];
        int sb = (int)csr[e + 8 + j];
        int sc = (int)csr[e + 16 + j];
        int sd = (int)csr[e + 24 + j];
        union { uint4 u4; __half2 h2[4]; } ga, gb, gc, gd;
        ga.u4 = *(const uint4*)(u + (size_t)sa * 64 + c * 8);
        gb.u4 = *(const uint4*)(u + (size_t)sb * 64 + c * 8);
        gc.u4 = *(const uint4*)(u + (size_t)sc * 64 + c * 8);
        gd.u4 = *(const uint4*)(u + (size_t)sd * 64 + c * 8);
#pragma unroll
        for (int i = 0; i < 4; ++i) {
            __half2 p = __hadd2(ga.h2[i], gb.h2[i]);
            __half2 qq = __hadd2(gc.h2[i], gd.h2[i]);
            float2 fp = __half22float2(p);
            float2 fq = __half22float2(qq);
            acc[2 * i]     += fp.x + fq.x;
            acc[2 * i + 1] += fp.y + fq.y;
        }
    }
    for (; e < e1; e += 8) {
        int sa = (int)csr[e + j];
        union { uint4 u4; __half2 h2[4]; } ga;
        ga.u4 = *(const uint4*)(u + (size_t)sa * 64 + c * 8);
#pragma unroll
        for (int i = 0; i < 4; ++i) {
            float2 fa = __half22float2(ga.h2[i]);
            acc[2 * i]     += fa.x;
            acc[2 * i + 1] += fa.y;
        }
    }
#pragma unroll
    for (int off = 8; off < 64; off <<= 1) {
#pragma unroll
        for (int i = 0; i < 8; ++i) acc[i] += __shfl_xor(acc[i], off);
    }
    if (j == 0) {                                 // 8 writer lanes, c=0..7; c>=6 write zero pad
        unsigned w0 = 0u, w1 = 0u;
        if (c < 6) {
            union { uint4 u4; __half2 h2[4]; } sv;
            sv.u4 = *(const uint4*)(u + (size_t)n * 64 + c * 8);
            float w2 = dinv2[n];
            float r0, r1, r2, r3, r4, r5, r6, r7;
            {
                float2 s0 = __half22float2(sv.h2[0]);
                float2 s1 = __half22float2(sv.h2[1]);
                float2 s2 = __half22float2(sv.h2[2]);
                float2 s3 = __half22float2(sv.h2[3]);
                r0 = (acc[0] + s0.x) * w2;  r1 = (acc[1] + s0.y) * w2;
                r2 = (acc[2] + s1.x) * w2;  r3 = (acc[3] + s1.y) * w2;
                r4 = (acc[4] + s2.x) * w2;  r5 = (acc[5] + s2.y) * w2;
                r6 = (acc[6] + s3.x) * w2;  r7 = (acc[7] + s3.y) * w2;
            }
            w0 = (unsigned)__builtin_amdgcn_cvt_pk_fp8_f32(r0, r1, 0, false);
            w0 = (unsigned)__builtin_amdgcn_cvt_pk_fp8_f32(r2, r3, (int)w0, true);
            w1 = (unsigned)__builtin_amdgcn_cvt_pk_fp8_f32(r4, r5, 0, false);
            w1 = (unsigned)__builtin_amdgcn_cvt_pk_fp8_f32(r6, r7, (int)w1, true);
        }
        *(uint2*)(un8 + (size_t)n * 64 + c * 8) = make_uint2(w0, w1);
    }
}

// ---------------- hop fp8->fp8: 64B rows (48 data + 16 pad), lane=j*4+c, 64-edge iter ----------------
// 4 requests/edge (was 8), 1 line/edge (was 2), table 3.2MB -> fits per-XCD L2 (FETCH -> ~0).

__global__ __launch_bounds__(256) void k_hop8(const unsigned char* __restrict__ u8,
                                              unsigned char* __restrict__ un8,
                                              const int* __restrict__ rowptr,
                                              const unsigned short* __restrict__ csr,
                                              const float* __restrict__ dinv2, int NT, int N) {
    int n = blockIdx.x * 4 + (threadIdx.x >> 6);
    if (n >= NT) return;
    const int lane = threadIdx.x & 63;
    const int c = lane & 3;         // 16B chunk = 16 fp8 cols (c=3 -> pad chunk, discarded)
    const int j = lane >> 2;        // edge slot 0..15

    float acc[16] = {0.f, 0.f, 0.f, 0.f, 0.f, 0.f, 0.f, 0.f,
                     0.f, 0.f, 0.f, 0.f, 0.f, 0.f, 0.f, 0.f};
    const int e0 = rowptr[n], e1 = rowptr[n + 1];
#define ACC4(B, W) do { unsigned _w = (W); \
    acc[B+0] += __builtin_amdgcn_cvt_f32_fp8((int)_w, 0); \
    acc[B+1] += __builtin_amdgcn_cvt_f32_fp8((int)_w, 1); \
    acc[B+2] += __builtin_amdgcn_cvt_f32_fp8((int)_w, 2); \
    acc[B+3] += __builtin_amdgcn_cvt_f32_fp8((int)_w, 3); } while (0)
    for (int e = e0; e < e1; e += 64) {
        const int rem = e1 - e;                       // multiple of 8, > 0
        int s0 = (j < rem)      ? (int)csr[e + j]      : N;  // sentinel row N is all-zero, L1-hot
        int s1 = (16 + j < rem) ? (int)csr[e + 16 + j] : N;
        int s2 = (32 + j < rem) ? (int)csr[e + 32 + j] : N;
        int s3 = (48 + j < rem) ? (int)csr[e + 48 + j] : N;
        uint4 g0 = *(const uint4*)(u8 + (size_t)s0 * 64 + c * 16);
        uint4 g1 = *(const uint4*)(u8 + (size_t)s1 * 64 + c * 16);
        uint4 g2 = *(const uint4*)(u8 + (size_t)s2 * 64 + c * 16);
        uint4 g3 = *(const uint4*)(u8 + (size_t)s3 * 64 + c * 16);
        ACC4(0, g0.x); ACC4(4, g0.y); ACC4(8, g0.z); ACC4(12, g0.w);
        ACC4(0, g1.x); ACC4(4, g1.y); ACC4(8, g1.z); ACC4(12, g1.w);
        ACC4(0, g2.x); ACC4(4, g2.y); ACC4(8, g2.z); ACC4(12, g2.w);
        ACC4(0, g3.x); ACC4(4, g3.y); ACC4(8, g3.z); ACC4(12, g3.w);
    }
#undef ACC4
    // reduce over edge slots j (lane bits 2..5), chunk c preserved
#pragma unroll
    for (int off = 4; off < 64; off <<= 1) {
#pragma unroll
        for (int i = 0; i < 16; ++i) acc[i] += __shfl_xor(acc[i], off);
    }
    if (lane < 4) {                                   // j==0 writers; c=lane; c==3 writes zero pad
        uint4 o = make_uint4(0u, 0u, 0u, 0u);
        if (lane < 3) {
            uint4 sv = *(const uint4*)(u8 + (size_t)n * 64 + lane * 16);
            float w2 = dinv2[n];
            float r0  = (acc[0]  + __builtin_amdgcn_cvt_f32_fp8((int)sv.x, 0)) * w2;
            float r1  = (acc[1]  + __builtin_amdgcn_cvt_f32_fp8((int)sv.x, 1)) * w2;
            float r2  = (acc[2]  + __builtin_amdgcn_cvt_f32_fp8((int)sv.x, 2)) * w2;
            float r3  = (acc[3]  + __builtin_amdgcn_cvt_f32_fp8((int)sv.x, 3)) * w2;
            float r4  = (acc[4]  + __builtin_amdgcn_cvt_f32_fp8((int)sv.y, 0)) * w2;
            float r5  = (acc[5]  + __builtin_amdgcn_cvt_f32_fp8((int)sv.y, 1)) * w2;
            float r6  = (acc[6]  + __builtin_amdgcn_cvt_f32_fp8((int)sv.y, 2)) * w2;
            float r7  = (acc[7]  + __builtin_amdgcn_cvt_f32_fp8((int)sv.y, 3)) * w2;
            float r8  = (acc[8]  + __builtin_amdgcn_cvt_f32_fp8((int)sv.z, 0)) * w2;
            float r9  = (acc[9]  + __builtin_amdgcn_cvt_f32_fp8((int)sv.z, 1)) * w2;
            float r10 = (acc[10] + __builtin_amdgcn_cvt_f32_fp8((int)sv.z, 2)) * w2;
            float r11 = (acc[11] + __builtin_amdgcn_cvt_f32_fp8((int)sv.z, 3)) * w2;
            float r12 = (acc[12] + __builtin_amdgcn_cvt_f32_fp8((int)sv.w, 0)) * w2;
            float r13 = (acc[13] + __builtin_amdgcn_cvt_f32_fp8((int)sv.w, 1)) * w2;
            float r14 = (acc[14] + __builtin_amdgcn_cvt_f32_fp8((int)sv.w, 2)) * w2;
            float r15 = (acc[15] + __builtin_amdgcn_cvt_f32_fp8((int)sv.w, 3)) * w2;
            o.x = (unsigned)__builtin_amdgcn_cvt_pk_fp8_f32(r0,  r1,  0, false);
            o.x = (unsigned)__builtin_amdgcn_cvt_pk_fp8_f32(r2,  r3,  (int)o.x, true);
            o.y = (unsigned)__builtin_amdgcn_cvt_pk_fp8_f32(r4,  r5,  0, false);
            o.y = (unsigned)__builtin_amdgcn_cvt_pk_fp8_f32(r6,  r7,  (int)o.y, true);
            o.z = (unsigned)__builtin_amdgcn_cvt_pk_fp8_f32(r8,  r9,  0, false);
            o.z = (unsigned)__builtin_amdgcn_cvt_pk_fp8_f32(r10, r11, (int)o.z, true);
            o.w = (unsigned)__builtin_amdgcn_cvt_pk_fp8_f32(r12, r13, 0, false);
            o.w = (unsigned)__builtin_amdgcn_cvt_pk_fp8_f32(r14, r15, (int)o.w, true);
        }
        *(uint4*)(un8 + (size_t)n * 64 + lane * 16) = o;
    }
}

// ---------------- final: out = log_softmax(sdeg * (temp0..2 . u_f16 + temp3..10 . u_fp8)) ----------------

__global__ __launch_bounds__(256) void k_final(const __half* __restrict__ u0, size_t S16,
                                               const unsigned char* __restrict__ w3, size_t S8B,
                                               const float* __restrict__ sdeg,
                                               const float* __restrict__ temp,
                                               float* __restrict__ out, int N) {
    int w = (blockIdx.x * 256 + threadIdx.x) >> 6;
    int lane = threadIdx.x & 63;
    if (w >= N) return;
    float val = 0.f, m = -INFINITY;
    if (lane < 48) {
        size_t base = (size_t)w * 64 + lane;
        float acc = temp[0] * __half2float(u0[base]);
        acc += temp[1] * __half2float(u0[base + S16]);
        acc += temp[2] * __half2float(u0[base + 2 * S16]);
        const unsigned char* p = w3 + (size_t)w * 64 + lane;
#pragma unroll
        for (int k = 3; k <= 10; ++k) {
            acc += temp[k] * __builtin_amdgcn_cvt_f32_fp8((int)*p, 0);
            p += S8B;
        }
        val = acc * sdeg[w];
        m = val;
    }
#pragma unroll
    for (int off = 32; off; off >>= 1) m = fmaxf(m, __shfl_xor(m, off));
    float ex = (lane < 48) ? __expf(val - m) : 0.f;
    float s = ex;
#pragma unroll
    for (int off = 32; off; off >>= 1) s += __shfl_xor(s, off);
    if (lane < 48) out[(size_t)w * 48 + lane] = val - m - __logf(s);
}

// ---------------- launch ----------------

extern "C" void kernel_launch(void* const* d_in, const int* in_sizes, int n_in,
                              void* d_out, int out_size, void* d_ws, size_t ws_size,
                              hipStream_t stream) {
    const float* x    = (const float*)d_in[0];
    const int*   ei   = (const int*)d_in[1];
    const float* W1   = (const float*)d_in[2];
    const float* b1   = (const float*)d_in[3];
    const float* W2   = (const float*)d_in[4];
    const float* b2   = (const float*)d_in[5];
    const float* temp = (const float*)d_in[6];
    float* out = (float*)d_out;

    const int N = in_sizes[0] / 256;
    const int E = in_sizes[1] / 2;
    const int* src = ei;
    const int* dst = ei + E;

    const int NT  = N + 1;                  // + sentinel node (rows kept zero)
    const int NT2 = N + 2;
    const int NB  = (NT + BNODES - 1) >> BSH;

    // workspace layout
    char* w8 = (char*)d_ws;
    size_t NP = (size_t)((NT2 + 63) & ~63);
    int*   cnt     = (int*)w8;                          // NP
    int*   bktcnt  = cnt + NP;                          // 128
    int*   rowptr  = bktcnt + 128;                      // NP
    int*   blk     = rowptr + NP;                       // 256
    float* dinv    = (float*)(blk + 256);               // NP
    float* dinv2   = dinv + NP;                         // NP
    float* sdeg    = dinv2 + NP;                        // NP
    unsigned short* csr = (unsigned short*)(sdeg + NP); // E + 8NT used (alloc E+32NT: OOB-read slack)
    size_t csr_i   = (((size_t)E + 32 * NT) / 2 + 32 + 63) & ~(size_t)63;  // ints
    unsigned short* w1t = (unsigned short*)((int*)(sdeg + NP) + csr_i);    // 65536 shorts
    unsigned short* w2t = w1t + 65536;                  // 12288 shorts (+pad)
    unsigned short* xb  = w2t + 12288 + 64;             // N*256 shorts
    size_t S16     = ((size_t)NT * 64 + 127) & ~(size_t)127;  // fp16 u-slab stride (halves, 128B rows)
    __half* u0     = (__half*)(xb + (size_t)N * 256);   // u0,u1,u2: 3*S16 halves
    unsigned short* h1b = (unsigned short*)(u0 + 3 * S16);   // N*256 shorts (gemm1 out)
    unsigned* stage = (unsigned*)h1b;                   // NB*CAP2 uints ⊂ h1b (dead pre-gemm)
    size_t S8B     = ((size_t)NT * 64 + 255) & ~(size_t)255; // fp8 slab stride (bytes, 64B rows)
    unsigned char* w3 = (unsigned char*)(h1b + (size_t)N * 256);  // w3..w10: 8*S8B bytes

    const int nbS = (NT2 + 255) / 256;

    // CSR build
    k_zero  <<<(int)((NP + 128 + 255) / 256), 256, 0, stream>>>(cnt, (int)(NP + 128));
    k_bin   <<<(E + ECHUNK - 1) / ECHUNK, 256, 0, stream>>>(src, dst, bktcnt, stage, E, NB);
    k_cnt   <<<NB, 512, 0, stream>>>(stage, bktcnt, cnt, dinv, dinv2, sdeg, N);
    k_scan1 <<<nbS, 256, 0, stream>>>(cnt, rowptr, blk, NT2);
    k_scan2 <<<1, 256, 0, stream>>>(blk, nbS);
    k_scan3 <<<nbS, 256, 0, stream>>>(rowptr, blk, NT2);
    k_place <<<NB, 512, 0, stream>>>(stage, bktcnt, rowptr, csr, N);

    // casts
    k_castx <<<(N * 256 / 8 + 255) / 256, 256, 0, stream>>>((const float4*)x, (uint4*)xb, N * 256 / 8);
    k_castw <<<(65536 + 12288 + 255) / 256, 256, 0, stream>>>(W1, W2, w1t, w2t);

    // MLP head on MFMA
    dim3 g1((N + 127) / 128, 2);
    k_mgemm1<<<g1, 256, 0, stream>>>(xb, w1t, b1, h1b, N);
    k_mgemm2<<<(N + 127) / 128, 256, 0, stream>>>(h1b, w2t, b2, dinv, u0, N);
    k_zero  <<<1, 64, 0, stream>>>((int*)(u0 + (size_t)N * 64), 24);   // sentinel u0 row (cols 0..47)

    // K-hop: hops 1-2 fp16 (weights 0.25/0.125), hop 3 fp16->fp8, hops 4-10 fp8 (weights <= 0.0625 total)
    const int hopBlocks = (NT + 3) / 4;
    k_hop16<<<hopBlocks, 256, 0, stream>>>(u0, u0 + S16, rowptr, csr, dinv2, NT);
    k_hop16<<<hopBlocks, 256, 0, stream>>>(u0 + S16, u0 + 2 * S16, rowptr, csr, dinv2, NT);
    k_hopm <<<hopBlocks, 256, 0, stream>>>(u0 + 2 * S16, w3, rowptr, csr, dinv2, NT);
    for (int k = 4; k <= 10; ++k)
        k_hop8<<<hopBlocks, 256, 0, stream>>>(w3 + (size_t)(k - 4) * S8B, w3 + (size_t)(k - 3) * S8B,
                                              rowptr, csr, dinv2, NT, N);

    k_final<<<(N + 3) / 4, 256, 0, stream>>>(u0, S16, w3, S8B, sdeg, temp, out, N);
}

// Round 11
// 538.730 us; speedup vs baseline: 1.1804x; 1.0044x over previous
//
#include <hip/hip_runtime.h>
#include <hip/hip_fp16.h>
#include <math.h>

#define BSH    9          // bucket = 512 nodes
#define BNODES 512
#define NBMAX  128
#define CAP2   24576      // per-bucket stage capacity
#define ECHUNK 6144       // edges per k_bin block

typedef short bf16x8 __attribute__((ext_vector_type(8)));
typedef float f32x4 __attribute__((ext_vector_type(4)));
typedef float f32x2 __attribute__((ext_vector_type(2)));

__device__ __forceinline__ unsigned f2b(float f) {   // float -> bf16 bits, RTN-even
    union { float f; unsigned u; } x; x.f = f;
    return (x.u + 0x7fffu + ((x.u >> 16) & 1u)) >> 16;
}

// ---------------- zero ----------------

__global__ __launch_bounds__(256) void k_zero(int* __restrict__ p, int n) {
    int i = blockIdx.x * 256 + threadIdx.x;
    if (i < n) p[i] = 0;
}

// ---------------- casts ----------------

__global__ __launch_bounds__(256) void k_castx(const float4* __restrict__ x, uint4* __restrict__ xb, int n8) {
    int i = blockIdx.x * 256 + threadIdx.x;
    if (i >= n8) return;
    float4 f0 = x[2 * i], f1 = x[2 * i + 1];
    uint4 o;
    o.x = f2b(f0.x) | (f2b(f0.y) << 16);
    o.y = f2b(f0.z) | (f2b(f0.w) << 16);
    o.z = f2b(f1.x) | (f2b(f1.y) << 16);
    o.w = f2b(f1.z) | (f2b(f1.w) << 16);
    xb[i] = o;
}

// fused: w1t[n*256+k]=bf16(W1[k*256+n]); w2t[n*256+k]=bf16(W2[k*48+n])
__global__ __launch_bounds__(256) void k_castw(const float* __restrict__ W1, const float* __restrict__ W2,
                                               unsigned short* __restrict__ w1t, unsigned short* __restrict__ w2t) {
    int i = blockIdx.x * 256 + threadIdx.x;
    if (i < 65536) {
        int n = i >> 8, k = i & 255;
        w1t[i] = (unsigned short)f2b(W1[k * 256 + n]);
    } else if (i < 65536 + 12288) {
        int j = i - 65536;
        int n = j >> 8, k = j & 255;
        w2t[j] = (unsigned short)f2b(W2[k * 48 + n]);
    }
}

// ---------------- pass 1: block-local binning by dst>>9 ----------------

__global__ __launch_bounds__(256) void k_bin(const int* __restrict__ src, const int* __restrict__ dst,
                                             int* __restrict__ bktcnt, unsigned* __restrict__ stage,
                                             int E, int NB) {
    __shared__ unsigned ecache[ECHUNK];
    __shared__ int lcnt[NBMAX], lbase[NBMAX], lcur[NBMAX];
    const int t = threadIdx.x;
    for (int i = t; i < NBMAX; i += 256) { lcnt[i] = 0; lcur[i] = 0; }
    const int e0 = blockIdx.x * ECHUNK;
    const int m = min(ECHUNK, E - e0);
    __syncthreads();
    for (int i = t; i < m; i += 256) {
        int s = src[e0 + i], d = dst[e0 + i];
        ecache[i] = ((unsigned)d << 16) | (unsigned)s;
        atomicAdd(&lcnt[d >> BSH], 1);
    }
    __syncthreads();
    if (t < NB) lbase[t] = lcnt[t] ? atomicAdd(&bktcnt[t], lcnt[t]) : 0;
    __syncthreads();
    for (int i = t; i < m; i += 256) {
        unsigned p = ecache[i];
        int b = (int)(p >> (16 + BSH));
        int pos = lbase[b] + atomicAdd(&lcur[b], 1);
        if (pos < CAP2) stage[(size_t)b * CAP2 + pos] = p;
    }
}

// ---------------- pass 2a: degrees per bucket + fused dinv/dinv2/sdeg ----------------

__global__ __launch_bounds__(512) void k_cnt(const unsigned* __restrict__ stage,
                                             const int* __restrict__ bktcnt,
                                             int* __restrict__ cnt,
                                             float* __restrict__ dinv, float* __restrict__ dinv2,
                                             float* __restrict__ sdeg, int N) {
    __shared__ int dcnt[BNODES];
    const int b = blockIdx.x, t = threadIdx.x;
    dcnt[t] = 0;
    __syncthreads();
    const int m = min(bktcnt[b], CAP2);
    const unsigned* st = stage + (size_t)b * CAP2;
    for (int i = t; i < m; i += 512)
        atomicAdd(&dcnt[(st[i] >> 16) & (BNODES - 1)], 1);
    __syncthreads();
    int node = b * BNODES + t;
    if (node <= N) {                       // include sentinel N (deg 0 -> row stays zero)
        int c = dcnt[t];
        cnt[node] = c;
        float d = (float)c + 1.0f;
        float r = rsqrtf(d);
        dinv[node] = r;
        dinv2[node] = r * r;
        sdeg[node] = d * r;
    }
}

// ---------------- scan over 8-padded row capacities ----------------

__global__ __launch_bounds__(256) void k_scan1(const int* __restrict__ cnt, int* __restrict__ rowptr,
                                               int* __restrict__ blk, int NT) {
    __shared__ int s[256];
    int t = threadIdx.x, i = blockIdx.x * 256 + t;
    int v = (i < NT) ? ((cnt[i] + 7) & ~7) : 0;   // pad rows to multiple of 8 (r2-proven)
    s[t] = v; __syncthreads();
#pragma unroll
    for (int off = 1; off < 256; off <<= 1) {
        int x = (t >= off) ? s[t - off] : 0; __syncthreads();
        s[t] += x; __syncthreads();
    }
    if (i < NT) rowptr[i] = s[t] - v;
    if (t == 255) blk[blockIdx.x] = s[255];
}

__global__ __launch_bounds__(256) void k_scan2(int* __restrict__ blk, int nb) {
    __shared__ int s[256];
    int t = threadIdx.x;
    int v = (t < nb) ? blk[t] : 0;
    s[t] = v; __syncthreads();
#pragma unroll
    for (int off = 1; off < 256; off <<= 1) {
        int x = (t >= off) ? s[t - off] : 0; __syncthreads();
        s[t] += x; __syncthreads();
    }
    if (t < nb) blk[t] = s[t] - v;
}

__global__ __launch_bounds__(256) void k_scan3(int* __restrict__ rowptr, const int* __restrict__ blk, int NT) {
    int i = blockIdx.x * 256 + threadIdx.x;
    if (i < NT) rowptr[i] += blk[blockIdx.x];
}

// ---------------- pass 2b: place into CSR (ushort) + pad ----------------

__global__ __launch_bounds__(512) void k_place(const unsigned* __restrict__ stage,
                                               const int* __restrict__ bktcnt,
                                               const int* __restrict__ rowptr,
                                               unsigned short* __restrict__ csr, int N) {
    __shared__ int lcur[BNODES];
    const int b = blockIdx.x, t = threadIdx.x;
    const int node = b * BNODES + t;
    lcur[t] = (node < N) ? rowptr[node] : 0;
    __syncthreads();
    const int m = min(bktcnt[b], CAP2);
    const unsigned* st = stage + (size_t)b * CAP2;
    for (int i = t; i < m; i += 512) {
        unsigned p = st[i];
        int dl = (int)((p >> 16) & (BNODES - 1));
        int pos = atomicAdd(&lcur[dl], 1);
        csr[pos] = (unsigned short)(p & 0xffffu);
    }
    __syncthreads();
    if (node < N) {
        int e1 = rowptr[node + 1];
        for (int i = lcur[t]; i < e1; ++i) csr[i] = (unsigned short)N;
    }
}

// ---------------- MFMA GEMM1: h1b = bf16(relu(xb @ W1 + b1)) ----------------

__global__ __launch_bounds__(256) void k_mgemm1(const unsigned short* __restrict__ xb,
                                                const unsigned short* __restrict__ w1t,
                                                const float* __restrict__ bias,
                                                unsigned short* __restrict__ h1b, int M) {
    __shared__ unsigned short sbuf[128 * 136];
    unsigned short* As = sbuf;
    unsigned short* Bs = sbuf + 128 * 40;
    const int t = threadIdx.x;
    const int bm = blockIdx.x * 128;
    const int bn = blockIdx.y * 128;
    const int w = t >> 6, lane = t & 63;
    const int q = lane >> 4, l16 = lane & 15;

    f32x4 acc[2][8] = {};
    const int ar0 = t >> 2;
    const int kc  = t & 3;
    const int swz_st = ((kc ^ (ar0 & 3)) * 8);
    int gr0 = bm + ar0;       if (gr0 >= M) gr0 = M - 1;
    int gr1 = bm + ar0 + 64;  if (gr1 >= M) gr1 = M - 1;
    const int swz_rd = (q ^ (l16 & 3)) * 8;

    for (int k0 = 0; k0 < 256; k0 += 32) {
        uint4 a0 = *(const uint4*)&xb[(size_t)gr0 * 256 + k0 + kc * 8];
        uint4 a1 = *(const uint4*)&xb[(size_t)gr1 * 256 + k0 + kc * 8];
        uint4 b0 = *(const uint4*)&w1t[(size_t)(bn + ar0) * 256 + k0 + kc * 8];
        uint4 b1 = *(const uint4*)&w1t[(size_t)(bn + ar0 + 64) * 256 + k0 + kc * 8];
        __syncthreads();
        *(uint4*)&As[ar0 * 40 + swz_st] = a0;
        *(uint4*)&As[(ar0 + 64) * 40 + swz_st] = a1;
        *(uint4*)&Bs[ar0 * 40 + swz_st] = b0;
        *(uint4*)&Bs[(ar0 + 64) * 40 + swz_st] = b1;
        __syncthreads();
        bf16x8 af0 = *(bf16x8*)&As[(w * 32 + l16) * 40 + swz_rd];
        bf16x8 af1 = *(bf16x8*)&As[(w * 32 + 16 + l16) * 40 + swz_rd];
#pragma unroll
        for (int j = 0; j < 8; ++j) {
            bf16x8 bf = *(bf16x8*)&Bs[(j * 16 + l16) * 40 + swz_rd];
            acc[0][j] = __builtin_amdgcn_mfma_f32_16x16x32_bf16(af0, bf, acc[0][j], 0, 0, 0);
            acc[1][j] = __builtin_amdgcn_mfma_f32_16x16x32_bf16(af1, bf, acc[1][j], 0, 0, 0);
        }
    }
    __syncthreads();
#pragma unroll
    for (int j = 0; j < 8; ++j) {
        int col = j * 16 + l16;
        float bb = bias[bn + col];
#pragma unroll
        for (int i = 0; i < 2; ++i) {
#pragma unroll
            for (int r = 0; r < 4; ++r) {
                float v = fmaxf(acc[i][j][r] + bb, 0.f);
                sbuf[(w * 32 + i * 16 + q * 4 + r) * 136 + col] = (unsigned short)f2b(v);
            }
        }
    }
    __syncthreads();
    const int row = t >> 1;
    const int ch = (t & 1) * 64;
    if (bm + row < M) {
#pragma unroll
        for (int i = 0; i < 8; ++i) {
            uint4 v = *(uint4*)&sbuf[row * 136 + ch + i * 8];
            *(uint4*)&h1b[(size_t)(bm + row) * 256 + bn + ch + i * 8] = v;
        }
    }
}

// ---------------- MFMA GEMM2: u0 = fp16(dinv .* (h1b @ W2 + b2)), row stride 64 halves ----------------

__global__ __launch_bounds__(256) void k_mgemm2(const unsigned short* __restrict__ h1b,
                                                const unsigned short* __restrict__ w2t,
                                                const float* __restrict__ bias,
                                                const float* __restrict__ dinv,
                                                __half* __restrict__ u0, int M) {
    __shared__ unsigned short As[128 * 40];
    __shared__ unsigned short Bs[48 * 40];
    const int t = threadIdx.x;
    const int bm = blockIdx.x * 128;
    const int w = t >> 6, lane = t & 63;
    const int q = lane >> 4, l16 = lane & 15;

    f32x4 acc[2][3] = {};
    const int ar0 = t >> 2;
    const int kc  = t & 3;
    const int swz_st = ((kc ^ (ar0 & 3)) * 8);
    int gr0 = bm + ar0;      if (gr0 >= M) gr0 = M - 1;
    int gr1 = bm + ar0 + 64; if (gr1 >= M) gr1 = M - 1;
    const int swz_rd = (q ^ (l16 & 3)) * 8;

    for (int k0 = 0; k0 < 256; k0 += 32) {
        uint4 a0 = *(const uint4*)&h1b[(size_t)gr0 * 256 + k0 + kc * 8];
        uint4 a1 = *(const uint4*)&h1b[(size_t)gr1 * 256 + k0 + kc * 8];
        uint4 bv;
        if (t < 192) bv = *(const uint4*)&w2t[(size_t)ar0 * 256 + k0 + kc * 8];
        __syncthreads();
        *(uint4*)&As[ar0 * 40 + swz_st] = a0;
        *(uint4*)&As[(ar0 + 64) * 40 + swz_st] = a1;
        if (t < 192) *(uint4*)&Bs[ar0 * 40 + swz_st] = bv;
        __syncthreads();
        bf16x8 af0 = *(bf16x8*)&As[(w * 32 + l16) * 40 + swz_rd];
        bf16x8 af1 = *(bf16x8*)&As[(w * 32 + 16 + l16) * 40 + swz_rd];
#pragma unroll
        for (int j = 0; j < 3; ++j) {
            bf16x8 bf = *(bf16x8*)&Bs[(j * 16 + l16) * 40 + swz_rd];
            acc[0][j] = __builtin_amdgcn_mfma_f32_16x16x32_bf16(af0, bf, acc[0][j], 0, 0, 0);
            acc[1][j] = __builtin_amdgcn_mfma_f32_16x16x32_bf16(af1, bf, acc[1][j], 0, 0, 0);
        }
    }
#pragma unroll
    for (int j = 0; j < 3; ++j) {
        int col = j * 16 + l16;
        float bb = bias[col];
#pragma unroll
        for (int i = 0; i < 2; ++i) {
#pragma unroll
            for (int r = 0; r < 4; ++r) {
                int row = bm + w * 32 + i * 16 + q * 4 + r;
                if (row < M) {
                    float v = (acc[i][j][r] + bb) * dinv[row];
                    u0[(size_t)row * 64 + col] = __float2half(v);
                }
            }
        }
    }
}

// ---------------- hop fp16->fp16 (r5-proven 33us structure): 128B rows, lane=j*8+c, 32+8 ----------------

__global__ __launch_bounds__(256) void k_hop16(const __half* __restrict__ u, __half* __restrict__ unxt,
                                               const int* __restrict__ rowptr,
                                               const unsigned short* __restrict__ csr,
                                               const float* __restrict__ dinv2, int NT) {
    int n = blockIdx.x * 4 + (threadIdx.x >> 6);
    if (n >= NT) return;
    const int lane = threadIdx.x & 63;
    const int c = lane & 7;
    const int j = lane >> 3;

    float acc[8] = {0.f, 0.f, 0.f, 0.f, 0.f, 0.f, 0.f, 0.f};
    const int e0 = rowptr[n], e1 = rowptr[n + 1];
    int e = e0;
    for (; e + 32 <= e1; e += 32) {
        int sa = (int)csr[e + j];
        int sb = (int)csr[e + 8 + j];
        int sc = (int)csr[e + 16 + j];
        int sd = (int)csr[e + 24 + j];
        union { uint4 u4; __half2 h2[4]; } ga, gb, gc, gd;
        ga.u4 = *(const uint4*)(u + (size_t)sa * 64 + c * 8);
        gb.u4 = *(const uint4*)(u + (size_t)sb * 64 + c * 8);
        gc.u4 = *(const uint4*)(u + (size_t)sc * 64 + c * 8);
        gd.u4 = *(const uint4*)(u + (size_t)sd * 64 + c * 8);
#pragma unroll
        for (int i = 0; i < 4; ++i) {
            __half2 p = __hadd2(ga.h2[i], gb.h2[i]);
            __half2 qq = __hadd2(gc.h2[i], gd.h2[i]);
            float2 fp = __half22float2(p);
            float2 fq = __half22float2(qq);
            acc[2 * i]     += fp.x + fq.x;
            acc[2 * i + 1] += fp.y + fq.y;
        }
    }
    for (; e < e1; e += 8) {
        int sa = (int)csr[e + j];
        union { uint4 u4; __half2 h2[4]; } ga;
        ga.u4 = *(const uint4*)(u + (size_t)sa * 64 + c * 8);
#pragma unroll
        for (int i = 0; i < 4; ++i) {
            float2 fa = __half22float2(ga.h2[i]);
            acc[2 * i]     += fa.x;
            acc[2 * i + 1] += fa.y;
        }
    }
#pragma unroll
    for (int off = 8; off < 64; off <<= 1) {
#pragma unroll
        for (int i = 0; i < 8; ++i) acc[i] += __shfl_xor(acc[i], off);
    }
    if (j == 0 && c < 6) {
        union { uint4 u4; __half2 h2[4]; } sv, ov;
        sv.u4 = *(const uint4*)(u + (size_t)n * 64 + c * 8);
        float w2 = dinv2[n];
#pragma unroll
        for (int i = 0; i < 4; ++i) {
            float2 sf = __half22float2(sv.h2[i]);
            float2 r;
            r.x = (acc[2 * i]     + sf.x) * w2;
            r.y = (acc[2 * i + 1] + sf.y) * w2;
            ov.h2[i] = __float22half2_rn(r);
        }
        *(uint4*)(unxt + (size_t)n * 64 + c * 8) = ov.u4;
    }
}

// ---------------- hop fp16->fp8: r5 gather, epilogue packs fp8 e4m3 into 64B rows ----------------

__global__ __launch_bounds__(256) void k_hopm(const __half* __restrict__ u, unsigned char* __restrict__ un8,
                                              const int* __restrict__ rowptr,
                                              const unsigned short* __restrict__ csr,
                                              const float* __restrict__ dinv2, int NT) {
    int n = blockIdx.x * 4 + (threadIdx.x >> 6);
    if (n >= NT) return;
    const int lane = threadIdx.x & 63;
    const int c = lane & 7;
    const int j = lane >> 3;

    float acc[8] = {0.f, 0.f, 0.f, 0.f, 0.f, 0.f, 0.f, 0.f};
    const int e0 = rowptr[n], e1 = rowptr[n + 1];
    int e = e0;
    for (; e + 32 <= e1; e += 32) {
        int sa = (int)csr[e + j];
        int sb = (int)csr[e + 8 + j];
        int sc = (int)csr[e + 16 + j];
        int sd = (int)csr[e + 24 + j];
        union { uint4 u4; __half2 h2[4]; } ga, gb, gc, gd;
        ga.u4 = *(const uint4*)(u + (size_t)sa * 64 + c * 8);
        gb.u4 = *(const uint4*)(u + (size_t)sb * 64 + c * 8);
        gc.u4 = *(const uint4*)(u + (size_t)sc * 64 + c * 8);
        gd.u4 = *(const uint4*)(u + (size_t)sd * 64 + c * 8);
#pragma unroll
        for (int i = 0; i < 4; ++i) {
            __half2 p = __hadd2(ga.h2[i], gb.h2[i]);
            __half2 qq = __hadd2(gc.h2[i], gd.h2[i]);
            float2 fp = __half22float2(p);
            float2 fq = __half22float2(qq);
            acc[2 * i]     += fp.x + fq.x;
            acc[2 * i + 1] += fp.y + fq.y;
        }
    }
    for (; e < e1; e += 8) {
        int sa = (int)csr[e + j];
        union { uint4 u4; __half2 h2[4]; } ga;
        ga.u4 = *(const uint4*)(u + (size_t)sa * 64 + c * 8);
#pragma unroll
        for (int i = 0; i < 4; ++i) {
            float2 fa = __half22float2(ga.h2[i]);
            acc[2 * i]     += fa.x;
            acc[2 * i + 1] += fa.y;
        }
    }
#pragma unroll
    for (int off = 8; off < 64; off <<= 1) {
#pragma unroll
        for (int i = 0; i < 8; ++i) acc[i] += __shfl_xor(acc[i], off);
    }
    if (j == 0) {                                 // 8 writer lanes, c=0..7; c>=6 write zero pad
        unsigned w0 = 0u, w1 = 0u;
        if (c < 6) {
            union { uint4 u4; __half2 h2[4]; } sv;
            sv.u4 = *(const uint4*)(u + (size_t)n * 64 + c * 8);
            float w2 = dinv2[n];
            float r0, r1, r2, r3, r4, r5, r6, r7;
            {
                float2 s0 = __half22float2(sv.h2[0]);
                float2 s1 = __half22float2(sv.h2[1]);
                float2 s2 = __half22float2(sv.h2[2]);
                float2 s3 = __half22float2(sv.h2[3]);
                r0 = (acc[0] + s0.x) * w2;  r1 = (acc[1] + s0.y) * w2;
                r2 = (acc[2] + s1.x) * w2;  r3 = (acc[3] + s1.y) * w2;
                r4 = (acc[4] + s2.x) * w2;  r5 = (acc[5] + s2.y) * w2;
                r6 = (acc[6] + s3.x) * w2;  r7 = (acc[7] + s3.y) * w2;
            }
            w0 = (unsigned)__builtin_amdgcn_cvt_pk_fp8_f32(r0, r1, 0, false);
            w0 = (unsigned)__builtin_amdgcn_cvt_pk_fp8_f32(r2, r3, (int)w0, true);
            w1 = (unsigned)__builtin_amdgcn_cvt_pk_fp8_f32(r4, r5, 0, false);
            w1 = (unsigned)__builtin_amdgcn_cvt_pk_fp8_f32(r6, r7, (int)w1, true);
        }
        *(uint2*)(un8 + (size_t)n * 64 + c * 8) = make_uint2(w0, w1);
    }
}

// ---------------- hop fp8->fp8: 64B rows, lane=j*4+c, 64-edge iter, PACKED converts ----------------
// r10 counters: VALUBusy 62.8% -> VALU-bound from 16 scalar cvt + 16 scalar add per gather.
// Fix: cvt_pk_f32_fp8 (2 elems/inst) + f32x2 accumulators (v_pk_add_f32 eligible):
// 8 cvt_pk + 8 packed adds per 16-elem gather. Memory side proven OK (FETCH 42.7->16.9MB).

__global__ __launch_bounds__(256) void k_hop8(const unsigned char* __restrict__ u8,
                                              unsigned char* __restrict__ un8,
                                              const int* __restrict__ rowptr,
                                              const unsigned short* __restrict__ csr,
                                              const float* __restrict__ dinv2, int NT, int N) {
    int n = blockIdx.x * 4 + (threadIdx.x >> 6);
    if (n >= NT) return;
    const int lane = threadIdx.x & 63;
    const int c = lane & 3;         // 16B chunk = 16 fp8 cols (c=3 -> pad chunk, discarded)
    const int j = lane >> 2;        // edge slot 0..15

    f32x2 acc2[8] = {};
    const int e0 = rowptr[n], e1 = rowptr[n + 1];
#define ACCW(B, W) do { unsigned _w = (W); \
    acc2[B]     += __builtin_amdgcn_cvt_pk_f32_fp8((int)_w, false); \
    acc2[(B)+1] += __builtin_amdgcn_cvt_pk_f32_fp8((int)_w, true); } while (0)
    for (int e = e0; e < e1; e += 64) {
        const int rem = e1 - e;                       // multiple of 8, > 0
        int s0 = (j < rem)      ? (int)csr[e + j]      : N;  // sentinel row N is all-zero, L1-hot
        int s1 = (16 + j < rem) ? (int)csr[e + 16 + j] : N;
        int s2 = (32 + j < rem) ? (int)csr[e + 32 + j] : N;
        int s3 = (48 + j < rem) ? (int)csr[e + 48 + j] : N;
        uint4 g0 = *(const uint4*)(u8 + (size_t)s0 * 64 + c * 16);
        uint4 g1 = *(const uint4*)(u8 + (size_t)s1 * 64 + c * 16);
        uint4 g2 = *(const uint4*)(u8 + (size_t)s2 * 64 + c * 16);
        uint4 g3 = *(const uint4*)(u8 + (size_t)s3 * 64 + c * 16);
        ACCW(0, g0.x); ACCW(2, g0.y); ACCW(4, g0.z); ACCW(6, g0.w);
        ACCW(0, g1.x); ACCW(2, g1.y); ACCW(4, g1.z); ACCW(6, g1.w);
        ACCW(0, g2.x); ACCW(2, g2.y); ACCW(4, g2.z); ACCW(6, g2.w);
        ACCW(0, g3.x); ACCW(2, g3.y); ACCW(4, g3.z); ACCW(6, g3.w);
    }
#undef ACCW
    // reduce over edge slots j (lane bits 2..5), chunk c preserved; packed adds
#pragma unroll
    for (int off = 4; off < 64; off <<= 1) {
#pragma unroll
        for (int i = 0; i < 8; ++i) {
            f32x2 t;
            t.x = __shfl_xor(acc2[i].x, off);
            t.y = __shfl_xor(acc2[i].y, off);
            acc2[i] += t;
        }
    }
    if (lane < 4) {                                   // j==0 writers; c=lane; c==3 writes zero pad
        uint4 o = make_uint4(0u, 0u, 0u, 0u);
        if (lane < 3) {
            uint4 sv = *(const uint4*)(u8 + (size_t)n * 64 + lane * 16);
            float w2 = dinv2[n];
            f32x2 s0l = __builtin_amdgcn_cvt_pk_f32_fp8((int)sv.x, false);
            f32x2 s0h = __builtin_amdgcn_cvt_pk_f32_fp8((int)sv.x, true);
            f32x2 s1l = __builtin_amdgcn_cvt_pk_f32_fp8((int)sv.y, false);
            f32x2 s1h = __builtin_amdgcn_cvt_pk_f32_fp8((int)sv.y, true);
            f32x2 s2l = __builtin_amdgcn_cvt_pk_f32_fp8((int)sv.z, false);
            f32x2 s2h = __builtin_amdgcn_cvt_pk_f32_fp8((int)sv.z, true);
            f32x2 s3l = __builtin_amdgcn_cvt_pk_f32_fp8((int)sv.w, false);
            f32x2 s3h = __builtin_amdgcn_cvt_pk_f32_fp8((int)sv.w, true);
            float r0  = (acc2[0].x + s0l.x) * w2;
            float r1  = (acc2[0].y + s0l.y) * w2;
            float r2  = (acc2[1].x + s0h.x) * w2;
            float r3  = (acc2[1].y + s0h.y) * w2;
            float r4  = (acc2[2].x + s1l.x) * w2;
            float r5  = (acc2[2].y + s1l.y) * w2;
            float r6  = (acc2[3].x + s1h.x) * w2;
            float r7  = (acc2[3].y + s1h.y) * w2;
            float r8  = (acc2[4].x + s2l.x) * w2;
            float r9  = (acc2[4].y + s2l.y) * w2;
            float r10 = (acc2[5].x + s2h.x) * w2;
            float r11 = (acc2[5].y + s2h.y) * w2;
            float r12 = (acc2[6].x + s3l.x) * w2;
            float r13 = (acc2[6].y + s3l.y) * w2;
            float r14 = (acc2[7].x + s3h.x) * w2;
            float r15 = (acc2[7].y + s3h.y) * w2;
            o.x = (unsigned)__builtin_amdgcn_cvt_pk_fp8_f32(r0,  r1,  0, false);
            o.x = (unsigned)__builtin_amdgcn_cvt_pk_fp8_f32(r2,  r3,  (int)o.x, true);
            o.y = (unsigned)__builtin_amdgcn_cvt_pk_fp8_f32(r4,  r5,  0, false);
            o.y = (unsigned)__builtin_amdgcn_cvt_pk_fp8_f32(r6,  r7,  (int)o.y, true);
            o.z = (unsigned)__builtin_amdgcn_cvt_pk_fp8_f32(r8,  r9,  0, false);
            o.z = (unsigned)__builtin_amdgcn_cvt_pk_fp8_f32(r10, r11, (int)o.z, true);
            o.w = (unsigned)__builtin_amdgcn_cvt_pk_fp8_f32(r12, r13, 0, false);
            o.w = (unsigned)__builtin_amdgcn_cvt_pk_fp8_f32(r14, r15, (int)o.w, true);
        }
        *(uint4*)(un8 + (size_t)n * 64 + lane * 16) = o;
    }
}

// ---------------- final: out = log_softmax(sdeg * (temp0..2 . u_f16 + temp3..10 . u_fp8)) ----------------

__global__ __launch_bounds__(256) void k_final(const __half* __restrict__ u0, size_t S16,
                                               const unsigned char* __restrict__ w3, size_t S8B,
                                               const float* __restrict__ sdeg,
                                               const float* __restrict__ temp,
                                               float* __restrict__ out, int N) {
    int w = (blockIdx.x * 256 + threadIdx.x) >> 6;
    int lane = threadIdx.x & 63;
    if (w >= N) return;
    float val = 0.f, m = -INFINITY;
    if (lane < 48) {
        size_t base = (size_t)w * 64 + lane;
        float acc = temp[0] * __half2float(u0[base]);
        acc += temp[1] * __half2float(u0[base + S16]);
        acc += temp[2] * __half2float(u0[base + 2 * S16]);
        const unsigned char* p = w3 + (size_t)w * 64 + lane;
#pragma unroll
        for (int k = 3; k <= 10; ++k) {
            acc += temp[k] * __builtin_amdgcn_cvt_f32_fp8((int)*p, 0);
            p += S8B;
        }
        val = acc * sdeg[w];
        m = val;
    }
#pragma unroll
    for (int off = 32; off; off >>= 1) m = fmaxf(m, __shfl_xor(m, off));
    float ex = (lane < 48) ? __expf(val - m) : 0.f;
    float s = ex;
#pragma unroll
    for (int off = 32; off; off >>= 1) s += __shfl_xor(s, off);
    if (lane < 48) out[(size_t)w * 48 + lane] = val - m - __logf(s);
}

// ---------------- launch ----------------

extern "C" void kernel_launch(void* const* d_in, const int* in_sizes, int n_in,
                              void* d_out, int out_size, void* d_ws, size_t ws_size,
                              hipStream_t stream) {
    const float* x    = (const float*)d_in[0];
    const int*   ei   = (const int*)d_in[1];
    const float* W1   = (const float*)d_in[2];
    const float* b1   = (const float*)d_in[3];
    const float* W2   = (const float*)d_in[4];
    const float* b2   = (const float*)d_in[5];
    const float* temp = (const float*)d_in[6];
    float* out = (float*)d_out;

    const int N = in_sizes[0] / 256;
    const int E = in_sizes[1] / 2;
    const int* src = ei;
    const int* dst = ei + E;

    const int NT  = N + 1;                  // + sentinel node (rows kept zero)
    const int NT2 = N + 2;
    const int NB  = (NT + BNODES - 1) >> BSH;

    // workspace layout
    char* w8 = (char*)d_ws;
    size_t NP = (size_t)((NT2 + 63) & ~63);
    int*   cnt     = (int*)w8;                          // NP
    int*   bktcnt  = cnt + NP;                          // 128
    int*   rowptr  = bktcnt + 128;                      // NP
    int*   blk     = rowptr + NP;                       // 256
    float* dinv    = (float*)(blk + 256);               // NP
    float* dinv2   = dinv + NP;                         // NP
    float* sdeg    = dinv2 + NP;                        // NP
    unsigned short* csr = (unsigned short*)(sdeg + NP); // E + 8NT used (alloc E+32NT: OOB-read slack)
    size_t csr_i   = (((size_t)E + 32 * NT) / 2 + 32 + 63) & ~(size_t)63;  // ints
    unsigned short* w1t = (unsigned short*)((int*)(sdeg + NP) + csr_i);    // 65536 shorts
    unsigned short* w2t = w1t + 65536;                  // 12288 shorts (+pad)
    unsigned short* xb  = w2t + 12288 + 64;             // N*256 shorts
    size_t S16     = ((size_t)NT * 64 + 127) & ~(size_t)127;  // fp16 u-slab stride (halves, 128B rows)
    __half* u0     = (__half*)(xb + (size_t)N * 256);   // u0,u1,u2: 3*S16 halves
    unsigned short* h1b = (unsigned short*)(u0 + 3 * S16);   // N*256 shorts (gemm1 out)
    unsigned* stage = (unsigned*)h1b;                   // NB*CAP2 uints ⊂ h1b (dead pre-gemm)
    size_t S8B     = ((size_t)NT * 64 + 255) & ~(size_t)255; // fp8 slab stride (bytes, 64B rows)
    unsigned char* w3 = (unsigned char*)(h1b + (size_t)N * 256);  // w3..w10: 8*S8B bytes

    const int nbS = (NT2 + 255) / 256;

    // CSR build
    k_zero  <<<(int)((NP + 128 + 255) / 256), 256, 0, stream>>>(cnt, (int)(NP + 128));
    k_bin   <<<(E + ECHUNK - 1) / ECHUNK, 256, 0, stream>>>(src, dst, bktcnt, stage, E, NB);
    k_cnt   <<<NB, 512, 0, stream>>>(stage, bktcnt, cnt, dinv, dinv2, sdeg, N);
    k_scan1 <<<nbS, 256, 0, stream>>>(cnt, rowptr, blk, NT2);
    k_scan2 <<<1, 256, 0, stream>>>(blk, nbS);
    k_scan3 <<<nbS, 256, 0, stream>>>(rowptr, blk, NT2);
    k_place <<<NB, 512, 0, stream>>>(stage, bktcnt, rowptr, csr, N);

    // casts
    k_castx <<<(N * 256 / 8 + 255) / 256, 256, 0, stream>>>((const float4*)x, (uint4*)xb, N * 256 / 8);
    k_castw <<<(65536 + 12288 + 255) / 256, 256, 0, stream>>>(W1, W2, w1t, w2t);

    // MLP head on MFMA
    dim3 g1((N + 127) / 128, 2);
    k_mgemm1<<<g1, 256, 0, stream>>>(xb, w1t, b1, h1b, N);
    k_mgemm2<<<(N + 127) / 128, 256, 0, stream>>>(h1b, w2t, b2, dinv, u0, N);
    k_zero  <<<1, 64, 0, stream>>>((int*)(u0 + (size_t)N * 64), 24);   // sentinel u0 row (cols 0..47)

    // K-hop: hops 1-2 fp16 (weights 0.25/0.125), hop 3 fp16->fp8, hops 4-10 fp8 (weights <= 0.0625 total)
    const int hopBlocks = (NT + 3) / 4;
    k_hop16<<<hopBlocks, 256, 0, stream>>>(u0, u0 + S16, rowptr, csr, dinv2, NT);
    k_hop16<<<hopBlocks, 256, 0, stream>>>(u0 + S16, u0 + 2 * S16, rowptr, csr, dinv2, NT);
    k_hopm <<<hopBlocks, 256, 0, stream>>>(u0 + 2 * S16, w3, rowptr, csr, dinv2, NT);
    for (int k = 4; k <= 10; ++k)
        k_hop8<<<hopBlocks, 256, 0, stream>>>(w3 + (size_t)(k - 4) * S8B, w3 + (size_t)(k - 3) * S8B,
                                              rowptr, csr, dinv2, NT, N);

    k_final<<<(N + 3) / 4, 256, 0, stream>>>(u0, S16, w3, S8B, sdeg, temp, out, N);
}

// Round 12
// 460.144 us; speedup vs baseline: 1.3820x; 1.1708x over previous
//
#include <hip/hip_runtime.h>
#include <hip/hip_fp16.h>
#include <math.h>

#define BSH    9          // bucket = 512 nodes
#define BNODES 512
#define NBMAX  128
#define CAP2   24576      // per-bucket stage capacity
#define ECHUNK 6144       // edges per k_bin block

typedef short bf16x8 __attribute__((ext_vector_type(8)));
typedef float f32x4 __attribute__((ext_vector_type(4)));

__device__ __forceinline__ unsigned f2b(float f) {   // float -> bf16 bits, RTN-even
    union { float f; unsigned u; } x; x.f = f;
    return (x.u + 0x7fffu + ((x.u >> 16) & 1u)) >> 16;
}

// ---------------- zero ----------------

__global__ __launch_bounds__(256) void k_zero(int* __restrict__ p, int n) {
    int i = blockIdx.x * 256 + threadIdx.x;
    if (i < n) p[i] = 0;
}

// ---------------- casts ----------------

__global__ __launch_bounds__(256) void k_castx(const float4* __restrict__ x, uint4* __restrict__ xb, int n8) {
    int i = blockIdx.x * 256 + threadIdx.x;
    if (i >= n8) return;
    float4 f0 = x[2 * i], f1 = x[2 * i + 1];
    uint4 o;
    o.x = f2b(f0.x) | (f2b(f0.y) << 16);
    o.y = f2b(f0.z) | (f2b(f0.w) << 16);
    o.z = f2b(f1.x) | (f2b(f1.y) << 16);
    o.w = f2b(f1.z) | (f2b(f1.w) << 16);
    xb[i] = o;
}

// fused: w1t[n*256+k]=bf16(W1[k*256+n]); w2t[n*256+k]=bf16(W2[k*48+n])
__global__ __launch_bounds__(256) void k_castw(const float* __restrict__ W1, const float* __restrict__ W2,
                                               unsigned short* __restrict__ w1t, unsigned short* __restrict__ w2t) {
    int i = blockIdx.x * 256 + threadIdx.x;
    if (i < 65536) {
        int n = i >> 8, k = i & 255;
        w1t[i] = (unsigned short)f2b(W1[k * 256 + n]);
    } else if (i < 65536 + 12288) {
        int j = i - 65536;
        int n = j >> 8, k = j & 255;
        w2t[j] = (unsigned short)f2b(W2[k * 48 + n]);
    }
}

// ---------------- pass 1: block-local binning by dst>>9 ----------------

__global__ __launch_bounds__(256) void k_bin(const int* __restrict__ src, const int* __restrict__ dst,
                                             int* __restrict__ bktcnt, unsigned* __restrict__ stage,
                                             int E, int NB) {
    __shared__ unsigned ecache[ECHUNK];
    __shared__ int lcnt[NBMAX], lbase[NBMAX], lcur[NBMAX];
    const int t = threadIdx.x;
    for (int i = t; i < NBMAX; i += 256) { lcnt[i] = 0; lcur[i] = 0; }
    const int e0 = blockIdx.x * ECHUNK;
    const int m = min(ECHUNK, E - e0);
    __syncthreads();
    for (int i = t; i < m; i += 256) {
        int s = src[e0 + i], d = dst[e0 + i];
        ecache[i] = ((unsigned)d << 16) | (unsigned)s;
        atomicAdd(&lcnt[d >> BSH], 1);
    }
    __syncthreads();
    if (t < NB) lbase[t] = lcnt[t] ? atomicAdd(&bktcnt[t], lcnt[t]) : 0;
    __syncthreads();
    for (int i = t; i < m; i += 256) {
        unsigned p = ecache[i];
        int b = (int)(p >> (16 + BSH));
        int pos = lbase[b] + atomicAdd(&lcur[b], 1);
        if (pos < CAP2) stage[(size_t)b * CAP2 + pos] = p;
    }
}

// ---------------- pass 2a: degrees per bucket + fused dinv/dinv2/sdeg ----------------

__global__ __launch_bounds__(512) void k_cnt(const unsigned* __restrict__ stage,
                                             const int* __restrict__ bktcnt,
                                             int* __restrict__ cnt,
                                             float* __restrict__ dinv, float* __restrict__ dinv2,
                                             float* __restrict__ sdeg, int N) {
    __shared__ int dcnt[BNODES];
    const int b = blockIdx.x, t = threadIdx.x;
    dcnt[t] = 0;
    __syncthreads();
    const int m = min(bktcnt[b], CAP2);
    const unsigned* st = stage + (size_t)b * CAP2;
    for (int i = t; i < m; i += 512)
        atomicAdd(&dcnt[(st[i] >> 16) & (BNODES - 1)], 1);
    __syncthreads();
    int node = b * BNODES + t;
    if (node <= N) {                       // include sentinel N (deg 0 -> row stays zero)
        int c = dcnt[t];
        cnt[node] = c;
        float d = (float)c + 1.0f;
        float r = rsqrtf(d);
        dinv[node] = r;
        dinv2[node] = r * r;
        sdeg[node] = d * r;
    }
}

// ---------------- scan over 8-padded row capacities ----------------

__global__ __launch_bounds__(256) void k_scan1(const int* __restrict__ cnt, int* __restrict__ rowptr,
                                               int* __restrict__ blk, int NT) {
    __shared__ int s[256];
    int t = threadIdx.x, i = blockIdx.x * 256 + t;
    int v = (i < NT) ? ((cnt[i] + 7) & ~7) : 0;   // pad rows to multiple of 8 (r2-proven: sentinels cheap)
    s[t] = v; __syncthreads();
#pragma unroll
    for (int off = 1; off < 256; off <<= 1) {
        int x = (t >= off) ? s[t - off] : 0; __syncthreads();
        s[t] += x; __syncthreads();
    }
    if (i < NT) rowptr[i] = s[t] - v;
    if (t == 255) blk[blockIdx.x] = s[255];
}

__global__ __launch_bounds__(256) void k_scan2(int* __restrict__ blk, int nb) {
    __shared__ int s[256];
    int t = threadIdx.x;
    int v = (t < nb) ? blk[t] : 0;
    s[t] = v; __syncthreads();
#pragma unroll
    for (int off = 1; off < 256; off <<= 1) {
        int x = (t >= off) ? s[t - off] : 0; __syncthreads();
        s[t] += x; __syncthreads();
    }
    if (t < nb) blk[t] = s[t] - v;
}

__global__ __launch_bounds__(256) void k_scan3(int* __restrict__ rowptr, const int* __restrict__ blk, int NT) {
    int i = blockIdx.x * 256 + threadIdx.x;
    if (i < NT) rowptr[i] += blk[blockIdx.x];
}

// ---------------- pass 2b: place into CSR (ushort) + pad ----------------

__global__ __launch_bounds__(512) void k_place(const unsigned* __restrict__ stage,
                                               const int* __restrict__ bktcnt,
                                               const int* __restrict__ rowptr,
                                               unsigned short* __restrict__ csr, int N) {
    __shared__ int lcur[BNODES];
    const int b = blockIdx.x, t = threadIdx.x;
    const int node = b * BNODES + t;
    lcur[t] = (node < N) ? rowptr[node] : 0;
    __syncthreads();
    const int m = min(bktcnt[b], CAP2);
    const unsigned* st = stage + (size_t)b * CAP2;
    for (int i = t; i < m; i += 512) {
        unsigned p = st[i];
        int dl = (int)((p >> 16) & (BNODES - 1));
        int pos = atomicAdd(&lcur[dl], 1);
        csr[pos] = (unsigned short)(p & 0xffffu);
    }
    __syncthreads();
    if (node < N) {
        int e1 = rowptr[node + 1];
        for (int i = lcur[t]; i < e1; ++i) csr[i] = (unsigned short)N;
    }
}

// ---------------- MFMA GEMM1: h1b = bf16(relu(xb @ W1 + b1)) ----------------
// 128x128 tile, BK=32; LDS-coalesced epilogue. (bf16 A input: fused-f32-cast variant measured slower, r2)

__global__ __launch_bounds__(256) void k_mgemm1(const unsigned short* __restrict__ xb,
                                                const unsigned short* __restrict__ w1t,
                                                const float* __restrict__ bias,
                                                unsigned short* __restrict__ h1b, int M) {
    __shared__ unsigned short sbuf[128 * 136];   // K-loop: As=first 5120, Bs=next 5120; epilogue: 128x136 tile
    unsigned short* As = sbuf;
    unsigned short* Bs = sbuf + 128 * 40;
    const int t = threadIdx.x;
    const int bm = blockIdx.x * 128;
    const int bn = blockIdx.y * 128;
    const int w = t >> 6, lane = t & 63;
    const int q = lane >> 4, l16 = lane & 15;

    f32x4 acc[2][8] = {};
    const int ar0 = t >> 2;
    const int kc  = t & 3;
    const int swz_st = ((kc ^ (ar0 & 3)) * 8);
    int gr0 = bm + ar0;       if (gr0 >= M) gr0 = M - 1;
    int gr1 = bm + ar0 + 64;  if (gr1 >= M) gr1 = M - 1;
    const int swz_rd = (q ^ (l16 & 3)) * 8;

    for (int k0 = 0; k0 < 256; k0 += 32) {
        uint4 a0 = *(const uint4*)&xb[(size_t)gr0 * 256 + k0 + kc * 8];
        uint4 a1 = *(const uint4*)&xb[(size_t)gr1 * 256 + k0 + kc * 8];
        uint4 b0 = *(const uint4*)&w1t[(size_t)(bn + ar0) * 256 + k0 + kc * 8];
        uint4 b1 = *(const uint4*)&w1t[(size_t)(bn + ar0 + 64) * 256 + k0 + kc * 8];
        __syncthreads();
        *(uint4*)&As[ar0 * 40 + swz_st] = a0;
        *(uint4*)&As[(ar0 + 64) * 40 + swz_st] = a1;
        *(uint4*)&Bs[ar0 * 40 + swz_st] = b0;
        *(uint4*)&Bs[(ar0 + 64) * 40 + swz_st] = b1;
        __syncthreads();
        bf16x8 af0 = *(bf16x8*)&As[(w * 32 + l16) * 40 + swz_rd];
        bf16x8 af1 = *(bf16x8*)&As[(w * 32 + 16 + l16) * 40 + swz_rd];
#pragma unroll
        for (int j = 0; j < 8; ++j) {
            bf16x8 bf = *(bf16x8*)&Bs[(j * 16 + l16) * 40 + swz_rd];
            acc[0][j] = __builtin_amdgcn_mfma_f32_16x16x32_bf16(af0, bf, acc[0][j], 0, 0, 0);
            acc[1][j] = __builtin_amdgcn_mfma_f32_16x16x32_bf16(af1, bf, acc[1][j], 0, 0, 0);
        }
    }
    // epilogue: fragments -> LDS tile -> coalesced 128B/thread stores
    __syncthreads();
#pragma unroll
    for (int j = 0; j < 8; ++j) {
        int col = j * 16 + l16;
        float bb = bias[bn + col];
#pragma unroll
        for (int i = 0; i < 2; ++i) {
#pragma unroll
            for (int r = 0; r < 4; ++r) {
                float v = fmaxf(acc[i][j][r] + bb, 0.f);
                sbuf[(w * 32 + i * 16 + q * 4 + r) * 136 + col] = (unsigned short)f2b(v);
            }
        }
    }
    __syncthreads();
    const int row = t >> 1;
    const int ch = (t & 1) * 64;
    if (bm + row < M) {
#pragma unroll
        for (int i = 0; i < 8; ++i) {
            uint4 v = *(uint4*)&sbuf[row * 136 + ch + i * 8];
            *(uint4*)&h1b[(size_t)(bm + row) * 256 + bn + ch + i * 8] = v;
        }
    }
}

// ---------------- MFMA GEMM2: u0 = fp16(dinv .* (h1b @ W2 + b2)), row stride 64 halves ----------------

__global__ __launch_bounds__(256) void k_mgemm2(const unsigned short* __restrict__ h1b,
                                                const unsigned short* __restrict__ w2t,
                                                const float* __restrict__ bias,
                                                const float* __restrict__ dinv,
                                                __half* __restrict__ u0, int M) {
    __shared__ unsigned short As[128 * 40];
    __shared__ unsigned short Bs[48 * 40];
    const int t = threadIdx.x;
    const int bm = blockIdx.x * 128;
    const int w = t >> 6, lane = t & 63;
    const int q = lane >> 4, l16 = lane & 15;

    f32x4 acc[2][3] = {};
    const int ar0 = t >> 2;
    const int kc  = t & 3;
    const int swz_st = ((kc ^ (ar0 & 3)) * 8);
    int gr0 = bm + ar0;      if (gr0 >= M) gr0 = M - 1;
    int gr1 = bm + ar0 + 64; if (gr1 >= M) gr1 = M - 1;
    const int swz_rd = (q ^ (l16 & 3)) * 8;

    for (int k0 = 0; k0 < 256; k0 += 32) {
        uint4 a0 = *(const uint4*)&h1b[(size_t)gr0 * 256 + k0 + kc * 8];
        uint4 a1 = *(const uint4*)&h1b[(size_t)gr1 * 256 + k0 + kc * 8];
        uint4 bv;
        if (t < 192) bv = *(const uint4*)&w2t[(size_t)ar0 * 256 + k0 + kc * 8];
        __syncthreads();
        *(uint4*)&As[ar0 * 40 + swz_st] = a0;
        *(uint4*)&As[(ar0 + 64) * 40 + swz_st] = a1;
        if (t < 192) *(uint4*)&Bs[ar0 * 40 + swz_st] = bv;
        __syncthreads();
        bf16x8 af0 = *(bf16x8*)&As[(w * 32 + l16) * 40 + swz_rd];
        bf16x8 af1 = *(bf16x8*)&As[(w * 32 + 16 + l16) * 40 + swz_rd];
#pragma unroll
        for (int j = 0; j < 3; ++j) {
            bf16x8 bf = *(bf16x8*)&Bs[(j * 16 + l16) * 40 + swz_rd];
            acc[0][j] = __builtin_amdgcn_mfma_f32_16x16x32_bf16(af0, bf, acc[0][j], 0, 0, 0);
            acc[1][j] = __builtin_amdgcn_mfma_f32_16x16x32_bf16(af1, bf, acc[1][j], 0, 0, 0);
        }
    }
#pragma unroll
    for (int j = 0; j < 3; ++j) {
        int col = j * 16 + l16;
        float bb = bias[col];
#pragma unroll
        for (int i = 0; i < 2; ++i) {
#pragma unroll
            for (int r = 0; r < 4; ++r) {
                int row = bm + w * 32 + i * 16 + q * 4 + r;
                if (row < M) {
                    float v = (acc[i][j][r] + bb) * dinv[row];
                    u0[(size_t)row * 64 + col] = __float2half(v);
                }
            }
        }
    }
}

// ---------------- quad-merged hop: 1 node/wave, lane = edge*8 + chunk (r5-proven best: 33us/hop) ----------------
// u-rows are 128B (2 aligned 64B lines). Aligned lane-quads read 4 consecutive 16B chunks of the
// SAME edge's line -> TA merges quad into one line-fill. 8 distinct rows per gather instruction is
// the proven TA sweet spot (r7/r11: 16-32 rows/inst costs ~14+ cy/row vs ~11). 32-edge main loop
// keeps 4 independent gathers in flight (r4: MLP=1 is latency death).
// Chunks 6,7 read row pad (garbage) -> reduction stays within same-c lanes; only j==0,c<6 writes.

__global__ __launch_bounds__(256) void k_hop(const __half* __restrict__ u, __half* __restrict__ unxt,
                                             const int* __restrict__ rowptr,
                                             const unsigned short* __restrict__ csr,
                                             const float* __restrict__ dinv2, int NT) {
    int n = blockIdx.x * 4 + (threadIdx.x >> 6);
    if (n >= NT) return;
    const int lane = threadIdx.x & 63;
    const int c = lane & 7;         // chunk of 8 halves (0..5 useful, 6..7 pad)
    const int j = lane >> 3;        // edge slot 0..7

    float acc[8] = {0.f, 0.f, 0.f, 0.f, 0.f, 0.f, 0.f, 0.f};
    const int e0 = rowptr[n], e1 = rowptr[n + 1];
    int e = e0;
    for (; e + 32 <= e1; e += 32) {
        int sa = (int)csr[e + j];
        int sb = (int)csr[e + 8 + j];
        int sc = (int)csr[e + 16 + j];
        int sd = (int)csr[e + 24 + j];
        union { uint4 u4; __half2 h2[4]; } ga, gb, gc, gd;
        ga.u4 = *(const uint4*)(u + (size_t)sa * 64 + c * 8);
        gb.u4 = *(const uint4*)(u + (size_t)sb * 64 + c * 8);
        gc.u4 = *(const uint4*)(u + (size_t)sc * 64 + c * 8);
        gd.u4 = *(const uint4*)(u + (size_t)sd * 64 + c * 8);
#pragma unroll
        for (int i = 0; i < 4; ++i) {
            __half2 p = __hadd2(ga.h2[i], gb.h2[i]);   // fp16 pairwise pre-add (r2-proven)
            __half2 qq = __hadd2(gc.h2[i], gd.h2[i]);
            float2 fp = __half22float2(p);
            float2 fq = __half22float2(qq);
            acc[2 * i]     += fp.x + fq.x;
            acc[2 * i + 1] += fp.y + fq.y;
        }
    }
    for (; e < e1; e += 8) {               // 8-edge tail (rows padded to mult of 8)
        int sa = (int)csr[e + j];
        union { uint4 u4; __half2 h2[4]; } ga;
        ga.u4 = *(const uint4*)(u + (size_t)sa * 64 + c * 8);
#pragma unroll
        for (int i = 0; i < 4; ++i) {
            float2 fa = __half22float2(ga.h2[i]);
            acc[2 * i]     += fa.x;
            acc[2 * i + 1] += fa.y;
        }
    }
    // reduce over edge slots j (lanes 8 apart, same chunk c)
#pragma unroll
    for (int off = 8; off < 64; off <<= 1) {
#pragma unroll
        for (int i = 0; i < 8; ++i) acc[i] += __shfl_xor(acc[i], off);
    }
    if (j == 0 && c < 6) {
        union { uint4 u4; __half2 h2[4]; } sv, ov;
        sv.u4 = *(const uint4*)(u + (size_t)n * 64 + c * 8);     // self-loop term
        float w2 = dinv2[n];
#pragma unroll
        for (int i = 0; i < 4; ++i) {
            float2 sf = __half22float2(sv.h2[i]);
            float2 r;
            r.x = (acc[2 * i]     + sf.x) * w2;
            r.y = (acc[2 * i + 1] + sf.y) * w2;
            ov.h2[i] = __float22half2_rn(r);
        }
        *(uint4*)(unxt + (size_t)n * 64 + c * 8) = ov.u4;
    }
}

// ---------------- final: out = log_softmax(sdeg * sum_k temp[k]*u_k), row stride 64 ----------------

__global__ __launch_bounds__(256) void k_final(const __half* __restrict__ u0, const __half* __restrict__ u1,
                                               size_t S, const float* __restrict__ sdeg,
                                               const float* __restrict__ temp,
                                               float* __restrict__ out, int N) {
    int w = (blockIdx.x * 256 + threadIdx.x) >> 6;
    int lane = threadIdx.x & 63;
    if (w >= N) return;
    size_t base = (size_t)w * 64 + lane;
    float val = 0.f, m = -INFINITY;
    if (lane < 48) {
        float acc = temp[0] * __half2float(u0[base]);
        const __half* uk = u1;
#pragma unroll
        for (int k = 1; k <= 10; ++k) {
            acc += temp[k] * __half2float(uk[base]);
            uk += S;
        }
        val = acc * sdeg[w];
        m = val;
    }
#pragma unroll
    for (int off = 32; off; off >>= 1) m = fmaxf(m, __shfl_xor(m, off));
    float ex = (lane < 48) ? __expf(val - m) : 0.f;
    float s = ex;
#pragma unroll
    for (int off = 32; off; off >>= 1) s += __shfl_xor(s, off);
    if (lane < 48) out[(size_t)w * 48 + lane] = val - m - __logf(s);
}

// ---------------- launch ----------------

extern "C" void kernel_launch(void* const* d_in, const int* in_sizes, int n_in,
                              void* d_out, int out_size, void* d_ws, size_t ws_size,
                              hipStream_t stream) {
    const float* x    = (const float*)d_in[0];
    const int*   ei   = (const int*)d_in[1];
    const float* W1   = (const float*)d_in[2];
    const float* b1   = (const float*)d_in[3];
    const float* W2   = (const float*)d_in[4];
    const float* b2   = (const float*)d_in[5];
    const float* temp = (const float*)d_in[6];
    float* out = (float*)d_out;

    const int N = in_sizes[0] / 256;
    const int E = in_sizes[1] / 2;
    const int* src = ei;
    const int* dst = ei + E;

    const int NT  = N + 1;                  // + sentinel node (u rows kept zero)
    const int NT2 = N + 2;
    const int NB  = (NT + BNODES - 1) >> BSH;

    // workspace layout
    char* w8 = (char*)d_ws;
    size_t NP = (size_t)((NT2 + 63) & ~63);
    int*   cnt     = (int*)w8;                          // NP (+128 bktcnt)
    int*   bktcnt  = cnt + NP;                          // 128
    int*   rowptr  = bktcnt + 128;                      // NP
    int*   blk     = rowptr + NP;                       // 256
    float* dinv    = (float*)(blk + 256);               // NP
    float* dinv2   = dinv + NP;                         // NP
    float* sdeg    = dinv2 + NP;                        // NP
    unsigned short* csr = (unsigned short*)(sdeg + NP); // E + 8*NT shorts used (alloc E+32*NT)
    size_t csr_i   = (((size_t)E + 32 * NT) / 2 + 32 + 63) & ~(size_t)63;  // ints
    unsigned short* w1t = (unsigned short*)((int*)(sdeg + NP) + csr_i);    // 65536 shorts
    unsigned short* w2t = w1t + 65536;                  // 12288 shorts (+pad)
    unsigned short* xb  = w2t + 12288 + 64;             // N*256 shorts (25.6MB)
    size_t S       = ((size_t)NT * 64 + 127) & ~(size_t)127;  // u-slab stride (halves, 128B rows)
    __half* u0     = (__half*)(xb + (size_t)N * 256);   // S halves
    unsigned short* h1b = (unsigned short*)(u0 + S);    // N*256 shorts (gemm1 out)
    unsigned* stage = (unsigned*)h1b;                   // NB*CAP2 uints ⊂ h1b (dead pre-gemm)
    __half* u1     = (__half*)(h1b + (size_t)N * 256);  // u1..u10 = 10*S halves

    const int nbS = (NT2 + 255) / 256;

    // CSR build
    k_zero  <<<(int)((NP + 128 + 255) / 256), 256, 0, stream>>>(cnt, (int)(NP + 128));
    k_bin   <<<(E + ECHUNK - 1) / ECHUNK, 256, 0, stream>>>(src, dst, bktcnt, stage, E, NB);
    k_cnt   <<<NB, 512, 0, stream>>>(stage, bktcnt, cnt, dinv, dinv2, sdeg, N);
    k_scan1 <<<nbS, 256, 0, stream>>>(cnt, rowptr, blk, NT2);
    k_scan2 <<<1, 256, 0, stream>>>(blk, nbS);
    k_scan3 <<<nbS, 256, 0, stream>>>(rowptr, blk, NT2);
    k_place <<<NB, 512, 0, stream>>>(stage, bktcnt, rowptr, csr, N);

    // casts
    k_castx <<<(N * 256 / 8 + 255) / 256, 256, 0, stream>>>((const float4*)x, (uint4*)xb, N * 256 / 8);
    k_castw <<<(65536 + 12288 + 255) / 256, 256, 0, stream>>>(W1, W2, w1t, w2t);

    // MLP head on MFMA
    dim3 g1((N + 127) / 128, 2);
    k_mgemm1<<<g1, 256, 0, stream>>>(xb, w1t, b1, h1b, N);
    k_mgemm2<<<(N + 127) / 128, 256, 0, stream>>>(h1b, w2t, b2, dinv, u0, N);
    k_zero  <<<1, 64, 0, stream>>>((int*)(u0 + (size_t)N * 64), 24);   // sentinel u0 row (cols 0..47)

    // K-hop propagation: quad-merged gather, 32-edge main + 8-edge tail
    const int hopBlocks = (NT + 3) / 4;
    for (int k = 0; k < 10; ++k) {
        const __half* cur = (k == 0) ? u0 : (u1 + (size_t)(k - 1) * S);
        __half* nxt = u1 + (size_t)k * S;
        k_hop<<<hopBlocks, 256, 0, stream>>>(cur, nxt, rowptr, csr, dinv2, NT);
    }

    k_final<<<(N + 3) / 4, 256, 0, stream>>>(u0, u1, S, sdeg, temp, out, N);
}